// Round 6
// baseline (737.530 us; speedup 1.0000x reference)
//
#include <hip/hip_runtime.h>
#include <stdint.h>

#define EPSV 1e-5f
#define INVT (1.0f/0.03f)

typedef _Float16 halfx8 __attribute__((ext_vector_type(8)));
typedef float f32x4 __attribute__((ext_vector_type(4)));

__device__ __forceinline__ unsigned short f2h(float f) {
  _Float16 h = (_Float16)f;
  return __builtin_bit_cast(unsigned short, h);
}

__device__ __forceinline__ float wave_sum(float v) {
  #pragma unroll
  for (int m = 32; m; m >>= 1) v += __shfl_xor(v, m);
  return v;
}
__device__ __forceinline__ float wave_max(float v) {
  #pragma unroll
  for (int m = 32; m; m >>= 1) v = fmaxf(v, __shfl_xor(v, m));
  return v;
}
// block = 256 threads = 4 waves
__device__ __forceinline__ float block_sum(float v, float* sred) {
  v = wave_sum(v);
  __syncthreads();
  if ((threadIdx.x & 63) == 0) sred[threadIdx.x >> 6] = v;
  __syncthreads();
  return sred[0] + sred[1] + sred[2] + sred[3];
}
__device__ __forceinline__ float block_max(float v, float* sred) {
  v = wave_max(v);
  __syncthreads();
  if ((threadIdx.x & 63) == 0) sred[threadIdx.x >> 6] = v;
  __syncthreads();
  return fmaxf(fmaxf(sred[0], sred[1]), fmaxf(sred[2], sred[3]));
}

__device__ __forceinline__ void gload_lds16(const void* g, void* l) {
  __builtin_amdgcn_global_load_lds((__attribute__((address_space(1))) void*)g,
                                   (__attribute__((address_space(3))) void*)l, 16, 0, 0);
}

// ================= fused prep =================
// b ranges: [0,96) lin1 | [96,416) gram | [416,800) f16-conv | [800,1376) WdT
//           [1376,1952) WbcT | [1952,2144) norms | [2144,2528) copies | [2528,2592) zero
__global__ __launch_bounds__(256) void k_prep(
    const float* __restrict__ code, const float* __restrict__ nl, const float* __restrict__ aug,
    const float* __restrict__ W1,
    unsigned short* __restrict__ code_f16, unsigned short* __restrict__ nl_f16,
    unsigned short* __restrict__ WdT, unsigned short* __restrict__ WbcT,
    unsigned short* __restrict__ lin1_f16,
    float* __restrict__ invc, float* __restrict__ invn, float* __restrict__ inva,
    float* __restrict__ G,
    float* __restrict__ out, float* __restrict__ s_sum, float* __restrict__ accv) {
  __shared__ __align__(16) float smem[4112];
  const int b = blockIdx.x, tid = threadIdx.x;

  if (b < 96) {
    // ---- lin1 = nl@(Wa+Wc), fp32 accum, f16 store ----
    const int rt = b / 12, ct = b % 12;
    const int r0 = rt * 32, c0 = ct * 64;
    float* Xs = smem;          // 32*33
    float* Ws = smem + 1056;   // 32*64
    const int tx = tid & 15, ty = tid >> 4;
    float a[2][4] = {};
    for (int kt = 0; kt < 24; ++kt) {
      const int k0 = kt * 32;
      __syncthreads();
      #pragma unroll
      for (int q = 0; q < 4; ++q) {
        int e = q * 256 + tid;
        int row = e >> 5, k = e & 31;
        Xs[row * 33 + k] = nl[(r0 + row) * 768 + k0 + k];
      }
      #pragma unroll
      for (int q = 0; q < 8; ++q) {
        int e = q * 256 + tid;
        int k = e >> 6, c = e & 63;
        Ws[k * 64 + c] = W1[(k0 + k) * 768 + c0 + c] + W1[(1536 + k0 + k) * 768 + c0 + c];
      }
      __syncthreads();
      #pragma unroll
      for (int k = 0; k < 32; ++k) {
        float xa = Xs[ty * 33 + k], xb = Xs[(ty + 16) * 33 + k];
        float w0 = Ws[k * 64 + tx], w1 = Ws[k * 64 + tx + 16];
        float w2 = Ws[k * 64 + tx + 32], w3 = Ws[k * 64 + tx + 48];
        a[0][0] += xa * w0; a[0][1] += xa * w1; a[0][2] += xa * w2; a[0][3] += xa * w3;
        a[1][0] += xb * w0; a[1][1] += xb * w1; a[1][2] += xb * w2; a[1][3] += xb * w3;
      }
    }
    #pragma unroll
    for (int dy = 0; dy < 2; ++dy)
      #pragma unroll
      for (int m = 0; m < 4; ++m)
        lin1_f16[(r0 + ty + dy * 16) * 768 + c0 + tx + m * 16] = f2h(a[dy][m]);

  } else if (b < 416) {
    // ---- 5 Gram matrices (fp32) ----
    const int bb = b - 96;
    const int mat = bb >> 6;
    const int tile = bb & 63;
    const int y0 = (tile >> 3) * 32, x0 = (tile & 7) * 32;
    const float* X; const float* Y;
    if (mat == 0)      { X = nl;   Y = code; }
    else if (mat == 1) { X = code; Y = code; }
    else if (mat == 2) { X = nl;   Y = nl;   }
    else if (mat == 3) { X = code; Y = aug;  }
    else               { X = nl;   Y = aug;  }
    float* outg = G + mat * 65536;
    float* Xs = smem;           // 32*64
    float* Ys = smem + 2048;    // 32*64
    const int tx = tid & 15, ty = tid >> 4;
    float a00 = 0, a01 = 0, a10 = 0, a11 = 0;
    for (int kt = 0; kt < 12; ++kt) {
      const int k0 = kt * 64;
      __syncthreads();
      #pragma unroll
      for (int q = 0; q < 2; ++q) {
        int chunk = q * 256 + tid;
        int row = chunk >> 4, c4 = chunk & 15;
        float4 xv = *(const float4*)(X + (y0 + row) * 768 + k0 + c4 * 4);
        float4 yv = *(const float4*)(Y + (x0 + row) * 768 + k0 + c4 * 4);
        *(float4*)(Xs + row * 64 + ((c4 ^ (row & 15)) << 2)) = xv;
        *(float4*)(Ys + row * 64 + ((c4 ^ (row & 15)) << 2)) = yv;
      }
      __syncthreads();
      #pragma unroll
      for (int c4 = 0; c4 < 16; ++c4) {
        float4 xa = *(const float4*)(Xs + ty * 64 + ((c4 ^ ty) << 2));
        float4 xb = *(const float4*)(Xs + (ty + 16) * 64 + ((c4 ^ ty) << 2));
        float4 ya = *(const float4*)(Ys + tx * 64 + ((c4 ^ tx) << 2));
        float4 yb = *(const float4*)(Ys + (tx + 16) * 64 + ((c4 ^ tx) << 2));
        a00 += xa.x * ya.x + xa.y * ya.y + xa.z * ya.z + xa.w * ya.w;
        a01 += xa.x * yb.x + xa.y * yb.y + xa.z * yb.z + xa.w * yb.w;
        a10 += xb.x * ya.x + xb.y * ya.y + xb.z * ya.z + xb.w * ya.w;
        a11 += xb.x * yb.x + xb.y * yb.y + xb.z * yb.z + xb.w * yb.w;
      }
    }
    outg[(y0 + ty) * 256 + x0 + tx] = a00;
    outg[(y0 + ty) * 256 + x0 + tx + 16] = a01;
    outg[(y0 + ty + 16) * 256 + x0 + tx] = a10;
    outg[(y0 + ty + 16) * 256 + x0 + tx + 16] = a11;

  } else if (b < 800) {
    // ---- fp32 -> f16 of code / nl ----
    const int idx = (b - 416) * 256 + tid;
    if (idx < 49152) {
      float4 v = ((const float4*)code)[idx];
      ushort4 o; o.x = f2h(v.x); o.y = f2h(v.y); o.z = f2h(v.z); o.w = f2h(v.w);
      ((ushort4*)code_f16)[idx] = o;
    } else {
      const int q = idx - 49152;
      float4 v = ((const float4*)nl)[q];
      ushort4 o; o.x = f2h(v.x); o.y = f2h(v.y); o.z = f2h(v.z); o.w = f2h(v.w);
      ((ushort4*)nl_f16)[q] = o;
    }

  } else if (b < 1376) {
    // ---- WdT[h][d] = f16(W1[2304+d][h]) ----
    float (*tile)[33] = (float(*)[33])smem;
    const int bb = b - 800;
    const int bx = bb % 24, by = bb / 24;
    const int tx = tid & 31, ty = tid >> 5;
    const int h0 = bx * 32, d0 = by * 32;
    #pragma unroll
    for (int yy = 0; yy < 4; ++yy) {
      int dd = ty + yy * 8;
      tile[dd][tx] = W1[(2304 + d0 + dd) * 768 + h0 + tx];
    }
    __syncthreads();
    #pragma unroll
    for (int yy = 0; yy < 4; ++yy) {
      int hh = ty + yy * 8;
      WdT[(h0 + hh) * 768 + d0 + tx] = f2h(tile[tx][hh]);
    }

  } else if (b < 1952) {
    // ---- WbcT[h][d] = f16(W1[768+d][h] - W1[1536+d][h]) ----
    float (*tile)[33] = (float(*)[33])smem;
    const int bb = b - 1376;
    const int bx = bb % 24, by = bb / 24;
    const int tx = tid & 31, ty = tid >> 5;
    const int h0 = bx * 32, d0 = by * 32;
    #pragma unroll
    for (int yy = 0; yy < 4; ++yy) {
      int dd = ty + yy * 8;
      tile[dd][tx] = W1[(768 + d0 + dd) * 768 + h0 + tx] - W1[(1536 + d0 + dd) * 768 + h0 + tx];
    }
    __syncthreads();
    #pragma unroll
    for (int yy = 0; yy < 4; ++yy) {
      int hh = ty + yy * 8;
      WbcT[(h0 + hh) * 768 + d0 + tx] = f2h(tile[tx][hh]);
    }

  } else if (b < 2144) {
    // ---- inverse norms, 1 wave per row ----
    const int rr = (b - 1952) * 4 + (tid >> 6);
    const int mat = rr >> 8, row = rr & 255;
    const float* src = (mat == 0) ? code : (mat == 1) ? nl : aug;
    const int l = tid & 63;
    float s = 0.f;
    #pragma unroll
    for (int t = 0; t < 12; ++t) { float v = src[row * 768 + l + t * 64]; s += v * v; }
    s = wave_sum(s);
    if (l == 0) ((mat == 0) ? invc : (mat == 1) ? invn : inva)[row] = rsqrtf(s);

  } else if (b < 2528) {
    // ---- verbatim output copies ----
    const int idx = (b - 2144) * 256 + tid;
    for (int t = idx; t < 196608; t += 384 * 256) {
      out[1 + t] = code[t];
      out[1 + 196608 + t] = nl[t];
    }

  } else {
    // ---- zero s_sum + acc ----
    const int idx = (b - 2528) * 256 + tid;
    ((float4*)s_sum)[idx] = make_float4(0.f, 0.f, 0.f, 0.f);
    if (b == 2528 && tid < 16) accv[tid] = 0.f;
  }
}

// ================= big pair kernel =================
// prod+lin2 [j,h] = sum_k code[j,k] * (nl[i,k]*Wd[k,h] + (Wb-Wc)[k,h])
// m97-style: SINGLE-buffered LDS (49 KB -> 3 blocks/CU), 2 barriers/kt,
// B'-input prefetch issued at compute-phase start (latency hides under MFMA).
// grid 1536 = 6 h-tiles x 256 i; block 512 thr = 8 waves (4 row x 2 col), tile 256j x 128h
__global__ __launch_bounds__(512, 6) void k_pair(
    const unsigned short* __restrict__ code_f16, const unsigned short* __restrict__ nl_f16,
    const unsigned short* __restrict__ WdT, const unsigned short* __restrict__ WbcT,
    const unsigned short* __restrict__ lin1_f16,
    const float* __restrict__ b1, const float* __restrict__ W2,
    float* __restrict__ s_sum) {
  __shared__ __align__(16) unsigned short Alds[256 * 64];   // 32 KB
  __shared__ __align__(16) unsigned short Blds[128 * 64];   // 16 KB
  __shared__ float linb[128];
  __shared__ float w2s[128];

  const int tid = threadIdx.x;
  const int bid = blockIdx.x;
  const int ct = bid >> 8;        // 0..5; a dispatch generation shares ct -> WdT/WbcT slice L2-hot
  const int i  = bid & 255;
  const int h0 = ct << 7;

  if (tid < 128) {
    linb[tid] = (float)((const _Float16*)lin1_f16)[i * 768 + h0 + tid] + b1[h0 + tid];
    w2s[tid]  = W2[h0 + tid];
  }

  const int w = tid >> 6, lane = tid & 63;
  const int lr = lane & 15, g = lane >> 4;
  const int wr = (w >> 1) << 6;   // 0,64,128,192
  const int wc = (w & 1) << 6;    // 0,64
  const int c4 = tid & 7, rg = tid >> 3;  // staging: k-chunk / row-group

  f32x4 acc[4][4] = {};

  auto stage_A = [&](int kt) {  // code tile 256x64 via async global_load_lds, LDS linear
    const int k0 = kt << 6;
    #pragma unroll
    for (int q = 0; q < 4; ++q) {
      const int chunk = q * 512 + tid;
      const int row = chunk >> 3, c = chunk & 7;
      const unsigned short* src = code_f16 + row * 768 + k0 + ((c ^ (row & 7)) << 3);
      char* dst = (char*)Alds + (q * 512 + w * 64) * 16;  // wave-uniform base + lane*16
      gload_lds16(src, dst);
    }
  };

  // B' staging, T14-split: loadB issues 5x dwordx4 early; writeB (pk_fma+ds_write) late.
  uint4 nv, wv0, wv1, bv0, bv1;
  auto loadB = [&](int kt) {
    const int k0 = kt << 6;
    nv  = *(const uint4*)(nl_f16 + i * 768 + k0 + (c4 << 3));
    wv0 = *(const uint4*)(WdT  + (h0 + rg) * 768 + k0 + (c4 << 3));
    bv0 = *(const uint4*)(WbcT + (h0 + rg) * 768 + k0 + (c4 << 3));
    wv1 = *(const uint4*)(WdT  + (h0 + rg + 64) * 768 + k0 + (c4 << 3));
    bv1 = *(const uint4*)(WbcT + (h0 + rg + 64) * 768 + k0 + (c4 << 3));
  };
  auto writeB = [&]() {
    uint4 p0, p1;
    asm("v_pk_fma_f16 %0, %1, %2, %3" : "=v"(p0.x) : "v"(nv.x), "v"(wv0.x), "v"(bv0.x));
    asm("v_pk_fma_f16 %0, %1, %2, %3" : "=v"(p0.y) : "v"(nv.y), "v"(wv0.y), "v"(bv0.y));
    asm("v_pk_fma_f16 %0, %1, %2, %3" : "=v"(p0.z) : "v"(nv.z), "v"(wv0.z), "v"(bv0.z));
    asm("v_pk_fma_f16 %0, %1, %2, %3" : "=v"(p0.w) : "v"(nv.w), "v"(wv0.w), "v"(bv0.w));
    asm("v_pk_fma_f16 %0, %1, %2, %3" : "=v"(p1.x) : "v"(nv.x), "v"(wv1.x), "v"(bv1.x));
    asm("v_pk_fma_f16 %0, %1, %2, %3" : "=v"(p1.y) : "v"(nv.y), "v"(wv1.y), "v"(bv1.y));
    asm("v_pk_fma_f16 %0, %1, %2, %3" : "=v"(p1.z) : "v"(nv.z), "v"(wv1.z), "v"(bv1.z));
    asm("v_pk_fma_f16 %0, %1, %2, %3" : "=v"(p1.w) : "v"(nv.w), "v"(wv1.w), "v"(bv1.w));
    const int r0 = rg, r1 = rg + 64;
    *(uint4*)((char*)Blds + r0 * 128 + ((c4 ^ (r0 & 7)) << 4)) = p0;
    *(uint4*)((char*)Blds + r1 * 128 + ((c4 ^ (r1 & 7)) << 4)) = p1;
  };

  loadB(0);
  for (int kt = 0; kt < 12; ++kt) {
    if (kt) __syncthreads();     // all reads of previous tile complete before overwrite
    stage_A(kt);                 // async gload_lds into Alds
    writeB();                    // compiler inserts counted vmcnt for the 5 prefetched loads
    __syncthreads();             // staging visible (vmcnt0+lgkmcnt0+barrier; other blocks cover)
    if (kt < 11) loadB(kt + 1);  // prefetch next B' inputs; latency hides under MFMA phase
    #pragma unroll
    for (int ks = 0; ks < 2; ++ks) {
      halfx8 bf[4];
      #pragma unroll
      for (int n = 0; n < 4; ++n) {
        const int row = wc + n * 16 + lr;
        bf[n] = *(const halfx8*)((const char*)Blds + row * 128 + (((ks * 4 + g) ^ (row & 7)) << 4));
      }
      #pragma unroll
      for (int m = 0; m < 4; ++m) {
        const int row = wr + m * 16 + lr;
        halfx8 af = *(const halfx8*)((const char*)Alds + row * 128 + (((ks * 4 + g) ^ (row & 7)) << 4));
        #pragma unroll
        for (int n = 0; n < 4; ++n)
          acc[m][n] = __builtin_amdgcn_mfma_f32_16x16x32_f16(af, bf[n], acc[m][n], 0, 0, 0);
      }
    }
  }

  // ---- epilogue: +lin1+b1 (lin2 folded into GEMM), tanh, *W2, h-reduce, atomic ----
  #pragma unroll
  for (int m = 0; m < 4; ++m) {
    #pragma unroll
    for (int reg = 0; reg < 4; ++reg) {
      const int rloc = wr + m * 16 + g * 4 + reg;   // j in 0..255
      float rs = 0.f;
      #pragma unroll
      for (int n = 0; n < 4; ++n) {
        const int cc = wc + n * 16 + lr;
        float x = acc[m][n][reg] + linb[cc];
        x = fminf(fmaxf(x, -15.f), 15.f);
        const float e = __expf(2.f * x);
        rs += __fdividef(e - 1.f, e + 1.f) * w2s[cc];
      }
      rs += __shfl_xor(rs, 1); rs += __shfl_xor(rs, 2);
      rs += __shfl_xor(rs, 4); rs += __shfl_xor(rs, 8);
      if (lr == 0) atomicAdd(&s_sum[i * 256 + rloc], rs);
    }
  }
}

// ================= fused losses =================
__global__ __launch_bounds__(256) void k_loss(const float* __restrict__ G,
    const float* __restrict__ invc, const float* __restrict__ invn, const float* __restrict__ inva,
    const float* __restrict__ s_sum, const float* __restrict__ b2, float* __restrict__ acc) {
  __shared__ float sred[4];
  __shared__ float dvals[3];
  const int t = threadIdx.x;
  if (blockIdx.x < 256) {
    const int i = blockIdx.x;
    const float* Snc = G;
    const float* Scc = G + 65536;
    const float* Snn = G + 131072;
    const float* Sca = G + 196608;
    const float* Sna = G + 262144;
    const float ici = invc[i], ini = invn[i];
    const float ict = invc[t], intt = invn[t], iat = inva[t];
    const float snc_it = Snc[i * 256 + t];
    const float snc_ti = Snc[t * 256 + i];
    const float e1 = snc_ti * ici * intt * INVT;
    const float e2 = (t == i) ? 0.f : 0.8f * INVT * Scc[i * 256 + t] * ici * ict;
    const float e3 = 0.1f * INVT * Sca[i * 256 + t] * ici * iat;
    const float f1 = snc_it * ini * ict * INVT;
    const float f2 = (t == i) ? 0.f : 0.8f * INVT * Snn[i * 256 + t] * ini * intt;
    const float f3 = 0.1f * INVT * Sna[i * 256 + t] * ini * iat;

    const float Mce = block_max(snc_it, sred);
    const float Mco = block_max(fmaxf(fmaxf(e1, e2), e3), sred);
    const float Mnl = block_max(fmaxf(fmaxf(f1, f2), f3), sred);
    const float Sce = block_sum(expf(snc_it - Mce), sred);
    const float Sco = block_sum(expf(e1 - Mco) + expf(e2 - Mco) + expf(e3 - Mco), sred);
    const float Snl = block_sum(expf(f1 - Mnl) + expf(f2 - Mnl) + expf(f3 - Mnl), sred);
    if (t == i) {
      dvals[0] = snc_it;
      dvals[1] = expf(e1 - Mco) + expf(e3 - Mco);
      dvals[2] = expf(f1 - Mnl) + expf(f3 - Mnl);
    }
    __syncthreads();
    if (t == 0) {
      atomicAdd(&acc[0], Mce + logf(Sce) - dvals[0]);
      atomicAdd(&acc[1], logf(Sco) - logf(dvals[1]));
      atomicAdd(&acc[2], logf(Snl) - logf(dvals[2]));
    }
  } else {
    const int r = (blockIdx.x - 256) * 256 + t;
    const int i = r >> 8, j = r & 255;
    const float s = s_sum[r] + b2[0];
    const float logit = 1.f / (1.f + expf(-s));
    const float pos = (i == j) ? logf(logit + EPSV) : 0.f;
    const float neg = (i == j) ? 0.f : logf(1.f - logit + EPSV);
    const float ps = block_sum(pos, sred);
    const float ns = block_sum(neg, sred);
    if (t == 0) { atomicAdd(&acc[3], ps); atomicAdd(&acc[4], ns); }
  }
}

// ================= final combine =================
__global__ void k_final(const float* __restrict__ acc, float* __restrict__ out) {
  if (threadIdx.x == 0 && blockIdx.x == 0) {
    const float lce = acc[0] * (1.f / 256.f);
    const float lclr = (acc[1] * (1.f / 256.f) + acc[2] * (1.f / 256.f)) * 0.5f;
    const float lcls = -(acc[4] * (1.f / (256.f * 255.f)) + acc[3] * (1.f / 256.f));
    out[0] = lce + 0.1f * lclr + lcls;
  }
}

extern "C" void kernel_launch(void* const* d_in, const int* in_sizes, int n_in,
                              void* d_out, int out_size, void* d_ws, size_t ws_size,
                              hipStream_t stream) {
  const float* code = (const float*)d_in[0];
  const float* nl   = (const float*)d_in[1];
  const float* aug  = (const float*)d_in[2];
  const float* W1   = (const float*)d_in[3];
  const float* b1   = (const float*)d_in[4];
  const float* W2   = (const float*)d_in[5];
  const float* b2   = (const float*)d_in[6];
  float* out = (float*)d_out;
  char* ws = (char*)d_ws;

  unsigned short* WdT      = (unsigned short*)(ws + 0);        // 1,179,648 B
  unsigned short* WbcT     = (unsigned short*)(ws + 1179648);  // 1,179,648 B
  unsigned short* code_f16 = (unsigned short*)(ws + 2359296);  // 393,216 B
  unsigned short* nl_f16   = (unsigned short*)(ws + 2752512);  // 393,216 B
  unsigned short* lin1_f16 = (unsigned short*)(ws + 3145728);  // 393,216 B
  float* G    = (float*)(ws + 3538944);                        // 1,310,720 B
  float* invc = (float*)(ws + 4849664);
  float* invn = (float*)(ws + 4850688);
  float* inva = (float*)(ws + 4851712);
  float* s_sum = (float*)(ws + 4852736);                       // 262,144 B
  float* acc   = (float*)(ws + 5114880);                       // 64 B  (total 5,114,944)

  k_prep<<<2592, 256, 0, stream>>>(code, nl, aug, W1, code_f16, nl_f16, WdT, WbcT,
                                   lin1_f16, invc, invn, inva, G, out, s_sum, acc);
  k_pair<<<1536, 512, 0, stream>>>(code_f16, nl_f16, WdT, WbcT, lin1_f16, b1, W2, s_sum);
  k_loss<<<512, 256, 0, stream>>>(G, invc, invn, inva, s_sum, b2, acc);
  k_final<<<1, 1, 0, stream>>>(acc, out);
}

// Round 8
// 262.953 us; speedup vs baseline: 2.8048x; 2.8048x over previous
//
#include <hip/hip_runtime.h>
#include <stdint.h>

#define EPSV 1e-5f
#define INVT (1.0f/0.03f)

typedef _Float16 halfx8 __attribute__((ext_vector_type(8)));
typedef float f32x4 __attribute__((ext_vector_type(4)));

__device__ __forceinline__ unsigned short f2h(float f) {
  _Float16 h = (_Float16)f;
  return __builtin_bit_cast(unsigned short, h);
}

__device__ __forceinline__ float wave_sum(float v) {
  #pragma unroll
  for (int m = 32; m; m >>= 1) v += __shfl_xor(v, m);
  return v;
}
__device__ __forceinline__ float wave_max(float v) {
  #pragma unroll
  for (int m = 32; m; m >>= 1) v = fmaxf(v, __shfl_xor(v, m));
  return v;
}
// block = 256 threads = 4 waves
__device__ __forceinline__ float block_sum(float v, float* sred) {
  v = wave_sum(v);
  __syncthreads();
  if ((threadIdx.x & 63) == 0) sred[threadIdx.x >> 6] = v;
  __syncthreads();
  return sred[0] + sred[1] + sred[2] + sred[3];
}
__device__ __forceinline__ float block_max(float v, float* sred) {
  v = wave_max(v);
  __syncthreads();
  if ((threadIdx.x & 63) == 0) sred[threadIdx.x >> 6] = v;
  __syncthreads();
  return fmaxf(fmaxf(sred[0], sred[1]), fmaxf(sred[2], sred[3]));
}

__device__ __forceinline__ void gload_lds16(const void* g, void* l) {
  __builtin_amdgcn_global_load_lds((__attribute__((address_space(1))) void*)g,
                                   (__attribute__((address_space(3))) void*)l, 16, 0, 0);
}

// ================= fused prep =================
// b ranges: [0,96) lin1 | [96,416) gram | [416,800) f16-conv | [800,1376) WdT
//           [1376,1952) WbcT | [1952,2144) norms | [2144,2528) copies | [2528,2592) zero
__global__ __launch_bounds__(256) void k_prep(
    const float* __restrict__ code, const float* __restrict__ nl, const float* __restrict__ aug,
    const float* __restrict__ W1,
    unsigned short* __restrict__ code_f16, unsigned short* __restrict__ nl_f16,
    unsigned short* __restrict__ WdT, unsigned short* __restrict__ WbcT,
    unsigned short* __restrict__ lin1_f16,
    float* __restrict__ invc, float* __restrict__ invn, float* __restrict__ inva,
    float* __restrict__ G,
    float* __restrict__ out, float* __restrict__ s_sum, float* __restrict__ accv) {
  __shared__ __align__(16) float smem[4112];
  const int b = blockIdx.x, tid = threadIdx.x;

  if (b < 96) {
    // ---- lin1 = nl@(Wa+Wc), fp32 accum, f16 store ----
    const int rt = b / 12, ct = b % 12;
    const int r0 = rt * 32, c0 = ct * 64;
    float* Xs = smem;          // 32*33
    float* Ws = smem + 1056;   // 32*64
    const int tx = tid & 15, ty = tid >> 4;
    float a[2][4] = {};
    for (int kt = 0; kt < 24; ++kt) {
      const int k0 = kt * 32;
      __syncthreads();
      #pragma unroll
      for (int q = 0; q < 4; ++q) {
        int e = q * 256 + tid;
        int row = e >> 5, k = e & 31;
        Xs[row * 33 + k] = nl[(r0 + row) * 768 + k0 + k];
      }
      #pragma unroll
      for (int q = 0; q < 8; ++q) {
        int e = q * 256 + tid;
        int k = e >> 6, c = e & 63;
        Ws[k * 64 + c] = W1[(k0 + k) * 768 + c0 + c] + W1[(1536 + k0 + k) * 768 + c0 + c];
      }
      __syncthreads();
      #pragma unroll
      for (int k = 0; k < 32; ++k) {
        float xa = Xs[ty * 33 + k], xb = Xs[(ty + 16) * 33 + k];
        float w0 = Ws[k * 64 + tx], w1 = Ws[k * 64 + tx + 16];
        float w2 = Ws[k * 64 + tx + 32], w3 = Ws[k * 64 + tx + 48];
        a[0][0] += xa * w0; a[0][1] += xa * w1; a[0][2] += xa * w2; a[0][3] += xa * w3;
        a[1][0] += xb * w0; a[1][1] += xb * w1; a[1][2] += xb * w2; a[1][3] += xb * w3;
      }
    }
    #pragma unroll
    for (int dy = 0; dy < 2; ++dy)
      #pragma unroll
      for (int m = 0; m < 4; ++m)
        lin1_f16[(r0 + ty + dy * 16) * 768 + c0 + tx + m * 16] = f2h(a[dy][m]);

  } else if (b < 416) {
    // ---- 5 Gram matrices (fp32) ----
    const int bb = b - 96;
    const int mat = bb >> 6;
    const int tile = bb & 63;
    const int y0 = (tile >> 3) * 32, x0 = (tile & 7) * 32;
    const float* X; const float* Y;
    if (mat == 0)      { X = nl;   Y = code; }
    else if (mat == 1) { X = code; Y = code; }
    else if (mat == 2) { X = nl;   Y = nl;   }
    else if (mat == 3) { X = code; Y = aug;  }
    else               { X = nl;   Y = aug;  }
    float* outg = G + mat * 65536;
    float* Xs = smem;           // 32*64
    float* Ys = smem + 2048;    // 32*64
    const int tx = tid & 15, ty = tid >> 4;
    float a00 = 0, a01 = 0, a10 = 0, a11 = 0;
    for (int kt = 0; kt < 12; ++kt) {
      const int k0 = kt * 64;
      __syncthreads();
      #pragma unroll
      for (int q = 0; q < 2; ++q) {
        int chunk = q * 256 + tid;
        int row = chunk >> 4, c4 = chunk & 15;
        float4 xv = *(const float4*)(X + (y0 + row) * 768 + k0 + c4 * 4);
        float4 yv = *(const float4*)(Y + (x0 + row) * 768 + k0 + c4 * 4);
        *(float4*)(Xs + row * 64 + ((c4 ^ (row & 15)) << 2)) = xv;
        *(float4*)(Ys + row * 64 + ((c4 ^ (row & 15)) << 2)) = yv;
      }
      __syncthreads();
      #pragma unroll
      for (int c4 = 0; c4 < 16; ++c4) {
        float4 xa = *(const float4*)(Xs + ty * 64 + ((c4 ^ ty) << 2));
        float4 xb = *(const float4*)(Xs + (ty + 16) * 64 + ((c4 ^ ty) << 2));
        float4 ya = *(const float4*)(Ys + tx * 64 + ((c4 ^ tx) << 2));
        float4 yb = *(const float4*)(Ys + (tx + 16) * 64 + ((c4 ^ tx) << 2));
        a00 += xa.x * ya.x + xa.y * ya.y + xa.z * ya.z + xa.w * ya.w;
        a01 += xa.x * yb.x + xa.y * yb.y + xa.z * yb.z + xa.w * yb.w;
        a10 += xb.x * ya.x + xb.y * ya.y + xb.z * ya.z + xb.w * ya.w;
        a11 += xb.x * yb.x + xb.y * yb.y + xb.z * yb.z + xb.w * yb.w;
      }
    }
    outg[(y0 + ty) * 256 + x0 + tx] = a00;
    outg[(y0 + ty) * 256 + x0 + tx + 16] = a01;
    outg[(y0 + ty + 16) * 256 + x0 + tx] = a10;
    outg[(y0 + ty + 16) * 256 + x0 + tx + 16] = a11;

  } else if (b < 800) {
    // ---- fp32 -> f16 of code / nl ----
    const int idx = (b - 416) * 256 + tid;
    if (idx < 49152) {
      float4 v = ((const float4*)code)[idx];
      ushort4 o; o.x = f2h(v.x); o.y = f2h(v.y); o.z = f2h(v.z); o.w = f2h(v.w);
      ((ushort4*)code_f16)[idx] = o;
    } else {
      const int q = idx - 49152;
      float4 v = ((const float4*)nl)[q];
      ushort4 o; o.x = f2h(v.x); o.y = f2h(v.y); o.z = f2h(v.z); o.w = f2h(v.w);
      ((ushort4*)nl_f16)[q] = o;
    }

  } else if (b < 1376) {
    // ---- WdT[h][d] = f16(W1[2304+d][h]) ----
    float (*tile)[33] = (float(*)[33])smem;
    const int bb = b - 800;
    const int bx = bb % 24, by = bb / 24;
    const int tx = tid & 31, ty = tid >> 5;
    const int h0 = bx * 32, d0 = by * 32;
    #pragma unroll
    for (int yy = 0; yy < 4; ++yy) {
      int dd = ty + yy * 8;
      tile[dd][tx] = W1[(2304 + d0 + dd) * 768 + h0 + tx];
    }
    __syncthreads();
    #pragma unroll
    for (int yy = 0; yy < 4; ++yy) {
      int hh = ty + yy * 8;
      WdT[(h0 + hh) * 768 + d0 + tx] = f2h(tile[tx][hh]);
    }

  } else if (b < 1952) {
    // ---- WbcT[h][d] = f16(W1[768+d][h] - W1[1536+d][h]) ----
    float (*tile)[33] = (float(*)[33])smem;
    const int bb = b - 1376;
    const int bx = bb % 24, by = bb / 24;
    const int tx = tid & 31, ty = tid >> 5;
    const int h0 = bx * 32, d0 = by * 32;
    #pragma unroll
    for (int yy = 0; yy < 4; ++yy) {
      int dd = ty + yy * 8;
      tile[dd][tx] = W1[(768 + d0 + dd) * 768 + h0 + tx] - W1[(1536 + d0 + dd) * 768 + h0 + tx];
    }
    __syncthreads();
    #pragma unroll
    for (int yy = 0; yy < 4; ++yy) {
      int hh = ty + yy * 8;
      WbcT[(h0 + hh) * 768 + d0 + tx] = f2h(tile[tx][hh]);
    }

  } else if (b < 2144) {
    // ---- inverse norms, 1 wave per row ----
    const int rr = (b - 1952) * 4 + (tid >> 6);
    const int mat = rr >> 8, row = rr & 255;
    const float* src = (mat == 0) ? code : (mat == 1) ? nl : aug;
    const int l = tid & 63;
    float s = 0.f;
    #pragma unroll
    for (int t = 0; t < 12; ++t) { float v = src[row * 768 + l + t * 64]; s += v * v; }
    s = wave_sum(s);
    if (l == 0) ((mat == 0) ? invc : (mat == 1) ? invn : inva)[row] = rsqrtf(s);

  } else if (b < 2528) {
    // ---- verbatim output copies ----
    const int idx = (b - 2144) * 256 + tid;
    for (int t = idx; t < 196608; t += 384 * 256) {
      out[1 + t] = code[t];
      out[1 + 196608 + t] = nl[t];
    }

  } else {
    // ---- zero s_sum + acc ----
    const int idx = (b - 2528) * 256 + tid;
    ((float4*)s_sum)[idx] = make_float4(0.f, 0.f, 0.f, 0.f);
    if (b == 2528 && tid < 16) accv[tid] = 0.f;
  }
}

// ================= big pair kernel =================
// prod+lin2 [j,h] = sum_k code[j,k] * (nl[i,k]*Wd[k,h] + (Wb-Wc)[k,h])
// m97-style: SINGLE-buffered LDS (49 KB -> 3 blocks/CU, LDS-limited), 2 barriers/kt.
// NO waves/EU bound: round 6's (512,6) capped VGPR at 40 -> acc spilled to scratch
// (FETCH 1.17 GB, MfmaUtil 5%). Plain (512) gave 88 VGPR / no spill in round 4.
// grid 1536 = 6 h-tiles x 256 i; block 512 thr = 8 waves (4 row x 2 col), tile 256j x 128h
__global__ __launch_bounds__(512) void k_pair(
    const unsigned short* __restrict__ code_f16, const unsigned short* __restrict__ nl_f16,
    const unsigned short* __restrict__ WdT, const unsigned short* __restrict__ WbcT,
    const unsigned short* __restrict__ lin1_f16,
    const float* __restrict__ b1, const float* __restrict__ W2,
    float* __restrict__ s_sum) {
  __shared__ __align__(16) unsigned short Alds[256 * 64];   // 32 KB
  __shared__ __align__(16) unsigned short Blds[128 * 64];   // 16 KB
  __shared__ float linb[128];
  __shared__ float w2s[128];

  const int tid = threadIdx.x;
  const int bid = blockIdx.x;
  const int ct = bid >> 8;        // 0..5; a dispatch generation shares ct -> WdT/WbcT slice L2-hot
  const int i  = bid & 255;
  const int h0 = ct << 7;

  if (tid < 128) {
    linb[tid] = (float)((const _Float16*)lin1_f16)[i * 768 + h0 + tid] + b1[h0 + tid];
    w2s[tid]  = W2[h0 + tid];
  }

  const int w = tid >> 6, lane = tid & 63;
  const int lr = lane & 15, g = lane >> 4;
  const int wr = (w >> 1) << 6;   // 0,64,128,192
  const int wc = (w & 1) << 6;    // 0,64
  const int c4 = tid & 7, rg = tid >> 3;  // staging: k-chunk / row-group

  f32x4 acc[4][4] = {};

  auto stage_A = [&](int kt) {  // code tile 256x64 via async global_load_lds, LDS linear
    const int k0 = kt << 6;
    #pragma unroll
    for (int q = 0; q < 4; ++q) {
      const int chunk = q * 512 + tid;
      const int row = chunk >> 3, c = chunk & 7;
      const unsigned short* src = code_f16 + row * 768 + k0 + ((c ^ (row & 7)) << 3);
      char* dst = (char*)Alds + (q * 512 + w * 64) * 16;  // wave-uniform base + lane*16
      gload_lds16(src, dst);
    }
  };

  // B' staging, T14-split: loadB issues 5x dwordx4 early; writeB (pk_fma+ds_write) late.
  uint4 nv, wv0, wv1, bv0, bv1;
  auto loadB = [&](int kt) {
    const int k0 = kt << 6;
    nv  = *(const uint4*)(nl_f16 + i * 768 + k0 + (c4 << 3));
    wv0 = *(const uint4*)(WdT  + (h0 + rg) * 768 + k0 + (c4 << 3));
    bv0 = *(const uint4*)(WbcT + (h0 + rg) * 768 + k0 + (c4 << 3));
    wv1 = *(const uint4*)(WdT  + (h0 + rg + 64) * 768 + k0 + (c4 << 3));
    bv1 = *(const uint4*)(WbcT + (h0 + rg + 64) * 768 + k0 + (c4 << 3));
  };
  auto writeB = [&]() {
    uint4 p0, p1;
    asm("v_pk_fma_f16 %0, %1, %2, %3" : "=v"(p0.x) : "v"(nv.x), "v"(wv0.x), "v"(bv0.x));
    asm("v_pk_fma_f16 %0, %1, %2, %3" : "=v"(p0.y) : "v"(nv.y), "v"(wv0.y), "v"(bv0.y));
    asm("v_pk_fma_f16 %0, %1, %2, %3" : "=v"(p0.z) : "v"(nv.z), "v"(wv0.z), "v"(bv0.z));
    asm("v_pk_fma_f16 %0, %1, %2, %3" : "=v"(p0.w) : "v"(nv.w), "v"(wv0.w), "v"(bv0.w));
    asm("v_pk_fma_f16 %0, %1, %2, %3" : "=v"(p1.x) : "v"(nv.x), "v"(wv1.x), "v"(bv1.x));
    asm("v_pk_fma_f16 %0, %1, %2, %3" : "=v"(p1.y) : "v"(nv.y), "v"(wv1.y), "v"(bv1.y));
    asm("v_pk_fma_f16 %0, %1, %2, %3" : "=v"(p1.z) : "v"(nv.z), "v"(wv1.z), "v"(bv1.z));
    asm("v_pk_fma_f16 %0, %1, %2, %3" : "=v"(p1.w) : "v"(nv.w), "v"(wv1.w), "v"(bv1.w));
    const int r0 = rg, r1 = rg + 64;
    *(uint4*)((char*)Blds + r0 * 128 + ((c4 ^ (r0 & 7)) << 4)) = p0;
    *(uint4*)((char*)Blds + r1 * 128 + ((c4 ^ (r1 & 7)) << 4)) = p1;
  };

  loadB(0);
  for (int kt = 0; kt < 12; ++kt) {
    if (kt) __syncthreads();     // all reads of previous tile complete before overwrite
    stage_A(kt);                 // async gload_lds into Alds
    writeB();                    // compiler inserts counted vmcnt for the 5 prefetched loads
    __syncthreads();             // staging visible (vmcnt0+lgkmcnt0+barrier; other blocks cover)
    if (kt < 11) loadB(kt + 1);  // prefetch next B' inputs; latency hides under MFMA phase
    #pragma unroll
    for (int ks = 0; ks < 2; ++ks) {
      halfx8 bf[4];
      #pragma unroll
      for (int n = 0; n < 4; ++n) {
        const int row = wc + n * 16 + lr;
        bf[n] = *(const halfx8*)((const char*)Blds + row * 128 + (((ks * 4 + g) ^ (row & 7)) << 4));
      }
      #pragma unroll
      for (int m = 0; m < 4; ++m) {
        const int row = wr + m * 16 + lr;
        halfx8 af = *(const halfx8*)((const char*)Alds + row * 128 + (((ks * 4 + g) ^ (row & 7)) << 4));
        #pragma unroll
        for (int n = 0; n < 4; ++n)
          acc[m][n] = __builtin_amdgcn_mfma_f32_16x16x32_f16(af, bf[n], acc[m][n], 0, 0, 0);
      }
    }
  }

  // ---- epilogue: +lin1+b1 (lin2 folded into GEMM), tanh, *W2, h-reduce, atomic ----
  #pragma unroll
  for (int m = 0; m < 4; ++m) {
    #pragma unroll
    for (int reg = 0; reg < 4; ++reg) {
      const int rloc = wr + m * 16 + g * 4 + reg;   // j in 0..255
      float rs = 0.f;
      #pragma unroll
      for (int n = 0; n < 4; ++n) {
        const int cc = wc + n * 16 + lr;
        float x = acc[m][n][reg] + linb[cc];
        x = fminf(fmaxf(x, -15.f), 15.f);
        const float e = __expf(2.f * x);
        rs += __fdividef(e - 1.f, e + 1.f) * w2s[cc];
      }
      rs += __shfl_xor(rs, 1); rs += __shfl_xor(rs, 2);
      rs += __shfl_xor(rs, 4); rs += __shfl_xor(rs, 8);
      if (lr == 0) atomicAdd(&s_sum[i * 256 + rloc], rs);
    }
  }
}

// ================= fused losses =================
__global__ __launch_bounds__(256) void k_loss(const float* __restrict__ G,
    const float* __restrict__ invc, const float* __restrict__ invn, const float* __restrict__ inva,
    const float* __restrict__ s_sum, const float* __restrict__ b2, float* __restrict__ acc) {
  __shared__ float sred[4];
  __shared__ float dvals[3];
  const int t = threadIdx.x;
  if (blockIdx.x < 256) {
    const int i = blockIdx.x;
    const float* Snc = G;
    const float* Scc = G + 65536;
    const float* Snn = G + 131072;
    const float* Sca = G + 196608;
    const float* Sna = G + 262144;
    const float ici = invc[i], ini = invn[i];
    const float ict = invc[t], intt = invn[t], iat = inva[t];
    const float snc_it = Snc[i * 256 + t];
    const float snc_ti = Snc[t * 256 + i];
    const float e1 = snc_ti * ici * intt * INVT;
    const float e2 = (t == i) ? 0.f : 0.8f * INVT * Scc[i * 256 + t] * ici * ict;
    const float e3 = 0.1f * INVT * Sca[i * 256 + t] * ici * iat;
    const float f1 = snc_it * ini * ict * INVT;
    const float f2 = (t == i) ? 0.f : 0.8f * INVT * Snn[i * 256 + t] * ini * intt;
    const float f3 = 0.1f * INVT * Sna[i * 256 + t] * ini * iat;

    const float Mce = block_max(snc_it, sred);
    const float Mco = block_max(fmaxf(fmaxf(e1, e2), e3), sred);
    const float Mnl = block_max(fmaxf(fmaxf(f1, f2), f3), sred);
    const float Sce = block_sum(expf(snc_it - Mce), sred);
    const float Sco = block_sum(expf(e1 - Mco) + expf(e2 - Mco) + expf(e3 - Mco), sred);
    const float Snl = block_sum(expf(f1 - Mnl) + expf(f2 - Mnl) + expf(f3 - Mnl), sred);
    if (t == i) {
      dvals[0] = snc_it;
      dvals[1] = expf(e1 - Mco) + expf(e3 - Mco);
      dvals[2] = expf(f1 - Mnl) + expf(f3 - Mnl);
    }
    __syncthreads();
    if (t == 0) {
      atomicAdd(&acc[0], Mce + logf(Sce) - dvals[0]);
      atomicAdd(&acc[1], logf(Sco) - logf(dvals[1]));
      atomicAdd(&acc[2], logf(Snl) - logf(dvals[2]));
    }
  } else {
    const int r = (blockIdx.x - 256) * 256 + t;
    const int i = r >> 8, j = r & 255;
    const float s = s_sum[r] + b2[0];
    const float logit = 1.f / (1.f + expf(-s));
    const float pos = (i == j) ? logf(logit + EPSV) : 0.f;
    const float neg = (i == j) ? 0.f : logf(1.f - logit + EPSV);
    const float ps = block_sum(pos, sred);
    const float ns = block_sum(neg, sred);
    if (t == 0) { atomicAdd(&acc[3], ps); atomicAdd(&acc[4], ns); }
  }
}

// ================= final combine =================
__global__ void k_final(const float* __restrict__ acc, float* __restrict__ out) {
  if (threadIdx.x == 0 && blockIdx.x == 0) {
    const float lce = acc[0] * (1.f / 256.f);
    const float lclr = (acc[1] * (1.f / 256.f) + acc[2] * (1.f / 256.f)) * 0.5f;
    const float lcls = -(acc[4] * (1.f / (256.f * 255.f)) + acc[3] * (1.f / 256.f));
    out[0] = lce + 0.1f * lclr + lcls;
  }
}

extern "C" void kernel_launch(void* const* d_in, const int* in_sizes, int n_in,
                              void* d_out, int out_size, void* d_ws, size_t ws_size,
                              hipStream_t stream) {
  const float* code = (const float*)d_in[0];
  const float* nl   = (const float*)d_in[1];
  const float* aug  = (const float*)d_in[2];
  const float* W1   = (const float*)d_in[3];
  const float* b1   = (const float*)d_in[4];
  const float* W2   = (const float*)d_in[5];
  const float* b2   = (const float*)d_in[6];
  float* out = (float*)d_out;
  char* ws = (char*)d_ws;

  unsigned short* WdT      = (unsigned short*)(ws + 0);        // 1,179,648 B
  unsigned short* WbcT     = (unsigned short*)(ws + 1179648);  // 1,179,648 B
  unsigned short* code_f16 = (unsigned short*)(ws + 2359296);  // 393,216 B
  unsigned short* nl_f16   = (unsigned short*)(ws + 2752512);  // 393,216 B
  unsigned short* lin1_f16 = (unsigned short*)(ws + 3145728);  // 393,216 B
  float* G    = (float*)(ws + 3538944);                        // 1,310,720 B
  float* invc = (float*)(ws + 4849664);
  float* invn = (float*)(ws + 4850688);
  float* inva = (float*)(ws + 4851712);
  float* s_sum = (float*)(ws + 4852736);                       // 262,144 B
  float* acc   = (float*)(ws + 5114880);                       // 64 B  (total 5,114,944)

  k_prep<<<2592, 256, 0, stream>>>(code, nl, aug, W1, code_f16, nl_f16, WdT, WbcT,
                                   lin1_f16, invc, invn, inva, G, out, s_sum, acc);
  k_pair<<<1536, 512, 0, stream>>>(code_f16, nl_f16, WdT, WbcT, lin1_f16, b1, W2, s_sum);
  k_loss<<<512, 256, 0, stream>>>(G, invc, invn, inva, s_sum, b2, acc);
  k_final<<<1, 1, 0, stream>>>(acc, out);
}

// Round 9
// 238.949 us; speedup vs baseline: 3.0866x; 1.1005x over previous
//
#include <hip/hip_runtime.h>
#include <stdint.h>

#define EPSV 1e-5f
#define INVT (1.0f/0.03f)

typedef _Float16 halfx8 __attribute__((ext_vector_type(8)));
typedef float f32x4 __attribute__((ext_vector_type(4)));

__device__ __forceinline__ unsigned short f2h(float f) {
  _Float16 h = (_Float16)f;
  return __builtin_bit_cast(unsigned short, h);
}

__device__ __forceinline__ float wave_sum(float v) {
  #pragma unroll
  for (int m = 32; m; m >>= 1) v += __shfl_xor(v, m);
  return v;
}
__device__ __forceinline__ float wave_max(float v) {
  #pragma unroll
  for (int m = 32; m; m >>= 1) v = fmaxf(v, __shfl_xor(v, m));
  return v;
}
// block = 256 threads = 4 waves
__device__ __forceinline__ float block_sum(float v, float* sred) {
  v = wave_sum(v);
  __syncthreads();
  if ((threadIdx.x & 63) == 0) sred[threadIdx.x >> 6] = v;
  __syncthreads();
  return sred[0] + sred[1] + sred[2] + sred[3];
}
__device__ __forceinline__ float block_max(float v, float* sred) {
  v = wave_max(v);
  __syncthreads();
  if ((threadIdx.x & 63) == 0) sred[threadIdx.x >> 6] = v;
  __syncthreads();
  return fmaxf(fmaxf(sred[0], sred[1]), fmaxf(sred[2], sred[3]));
}

__device__ __forceinline__ void gload_lds16(const void* g, void* l) {
  __builtin_amdgcn_global_load_lds((__attribute__((address_space(1))) void*)g,
                                   (__attribute__((address_space(3))) void*)l, 16, 0, 0);
}

// ================= fused prep =================
// b ranges: [0,96) lin1 | [96,416) gram | [416,800) f16-conv | [800,1376) WdT
//           [1376,1952) WbcT | [1952,2144) norms | [2144,2528) copies | [2528,2592) zero
__global__ __launch_bounds__(256) void k_prep(
    const float* __restrict__ code, const float* __restrict__ nl, const float* __restrict__ aug,
    const float* __restrict__ W1,
    unsigned short* __restrict__ code_f16, unsigned short* __restrict__ nl_f16,
    unsigned short* __restrict__ WdT, unsigned short* __restrict__ WbcT,
    unsigned short* __restrict__ lin1_f16,
    float* __restrict__ invc, float* __restrict__ invn, float* __restrict__ inva,
    float* __restrict__ G,
    float* __restrict__ out, float* __restrict__ s_sum, float* __restrict__ accv) {
  __shared__ __align__(16) float smem[4112];
  const int b = blockIdx.x, tid = threadIdx.x;

  if (b < 96) {
    // ---- lin1 = nl@(Wa+Wc), fp32 accum, f16 store ----
    const int rt = b / 12, ct = b % 12;
    const int r0 = rt * 32, c0 = ct * 64;
    float* Xs = smem;          // 32*33
    float* Ws = smem + 1056;   // 32*64
    const int tx = tid & 15, ty = tid >> 4;
    float a[2][4] = {};
    for (int kt = 0; kt < 24; ++kt) {
      const int k0 = kt * 32;
      __syncthreads();
      #pragma unroll
      for (int q = 0; q < 4; ++q) {
        int e = q * 256 + tid;
        int row = e >> 5, k = e & 31;
        Xs[row * 33 + k] = nl[(r0 + row) * 768 + k0 + k];
      }
      #pragma unroll
      for (int q = 0; q < 8; ++q) {
        int e = q * 256 + tid;
        int k = e >> 6, c = e & 63;
        Ws[k * 64 + c] = W1[(k0 + k) * 768 + c0 + c] + W1[(1536 + k0 + k) * 768 + c0 + c];
      }
      __syncthreads();
      #pragma unroll
      for (int k = 0; k < 32; ++k) {
        float xa = Xs[ty * 33 + k], xb = Xs[(ty + 16) * 33 + k];
        float w0 = Ws[k * 64 + tx], w1 = Ws[k * 64 + tx + 16];
        float w2 = Ws[k * 64 + tx + 32], w3 = Ws[k * 64 + tx + 48];
        a[0][0] += xa * w0; a[0][1] += xa * w1; a[0][2] += xa * w2; a[0][3] += xa * w3;
        a[1][0] += xb * w0; a[1][1] += xb * w1; a[1][2] += xb * w2; a[1][3] += xb * w3;
      }
    }
    #pragma unroll
    for (int dy = 0; dy < 2; ++dy)
      #pragma unroll
      for (int m = 0; m < 4; ++m)
        lin1_f16[(r0 + ty + dy * 16) * 768 + c0 + tx + m * 16] = f2h(a[dy][m]);

  } else if (b < 416) {
    // ---- 5 Gram matrices (fp32) ----
    const int bb = b - 96;
    const int mat = bb >> 6;
    const int tile = bb & 63;
    const int y0 = (tile >> 3) * 32, x0 = (tile & 7) * 32;
    const float* X; const float* Y;
    if (mat == 0)      { X = nl;   Y = code; }
    else if (mat == 1) { X = code; Y = code; }
    else if (mat == 2) { X = nl;   Y = nl;   }
    else if (mat == 3) { X = code; Y = aug;  }
    else               { X = nl;   Y = aug;  }
    float* outg = G + mat * 65536;
    float* Xs = smem;           // 32*64
    float* Ys = smem + 2048;    // 32*64
    const int tx = tid & 15, ty = tid >> 4;
    float a00 = 0, a01 = 0, a10 = 0, a11 = 0;
    for (int kt = 0; kt < 12; ++kt) {
      const int k0 = kt * 64;
      __syncthreads();
      #pragma unroll
      for (int q = 0; q < 2; ++q) {
        int chunk = q * 256 + tid;
        int row = chunk >> 4, c4 = chunk & 15;
        float4 xv = *(const float4*)(X + (y0 + row) * 768 + k0 + c4 * 4);
        float4 yv = *(const float4*)(Y + (x0 + row) * 768 + k0 + c4 * 4);
        *(float4*)(Xs + row * 64 + ((c4 ^ (row & 15)) << 2)) = xv;
        *(float4*)(Ys + row * 64 + ((c4 ^ (row & 15)) << 2)) = yv;
      }
      __syncthreads();
      #pragma unroll
      for (int c4 = 0; c4 < 16; ++c4) {
        float4 xa = *(const float4*)(Xs + ty * 64 + ((c4 ^ ty) << 2));
        float4 xb = *(const float4*)(Xs + (ty + 16) * 64 + ((c4 ^ ty) << 2));
        float4 ya = *(const float4*)(Ys + tx * 64 + ((c4 ^ tx) << 2));
        float4 yb = *(const float4*)(Ys + (tx + 16) * 64 + ((c4 ^ tx) << 2));
        a00 += xa.x * ya.x + xa.y * ya.y + xa.z * ya.z + xa.w * ya.w;
        a01 += xa.x * yb.x + xa.y * yb.y + xa.z * yb.z + xa.w * yb.w;
        a10 += xb.x * ya.x + xb.y * ya.y + xb.z * ya.z + xb.w * ya.w;
        a11 += xb.x * yb.x + xb.y * yb.y + xb.z * yb.z + xb.w * yb.w;
      }
    }
    outg[(y0 + ty) * 256 + x0 + tx] = a00;
    outg[(y0 + ty) * 256 + x0 + tx + 16] = a01;
    outg[(y0 + ty + 16) * 256 + x0 + tx] = a10;
    outg[(y0 + ty + 16) * 256 + x0 + tx + 16] = a11;

  } else if (b < 800) {
    // ---- fp32 -> f16 of code / nl ----
    const int idx = (b - 416) * 256 + tid;
    if (idx < 49152) {
      float4 v = ((const float4*)code)[idx];
      ushort4 o; o.x = f2h(v.x); o.y = f2h(v.y); o.z = f2h(v.z); o.w = f2h(v.w);
      ((ushort4*)code_f16)[idx] = o;
    } else {
      const int q = idx - 49152;
      float4 v = ((const float4*)nl)[q];
      ushort4 o; o.x = f2h(v.x); o.y = f2h(v.y); o.z = f2h(v.z); o.w = f2h(v.w);
      ((ushort4*)nl_f16)[q] = o;
    }

  } else if (b < 1376) {
    // ---- WdT[h][d] = f16(W1[2304+d][h]) ----
    float (*tile)[33] = (float(*)[33])smem;
    const int bb = b - 800;
    const int bx = bb % 24, by = bb / 24;
    const int tx = tid & 31, ty = tid >> 5;
    const int h0 = bx * 32, d0 = by * 32;
    #pragma unroll
    for (int yy = 0; yy < 4; ++yy) {
      int dd = ty + yy * 8;
      tile[dd][tx] = W1[(2304 + d0 + dd) * 768 + h0 + tx];
    }
    __syncthreads();
    #pragma unroll
    for (int yy = 0; yy < 4; ++yy) {
      int hh = ty + yy * 8;
      WdT[(h0 + hh) * 768 + d0 + tx] = f2h(tile[tx][hh]);
    }

  } else if (b < 1952) {
    // ---- WbcT[h][d] = f16(W1[768+d][h] - W1[1536+d][h]) ----
    float (*tile)[33] = (float(*)[33])smem;
    const int bb = b - 1376;
    const int bx = bb % 24, by = bb / 24;
    const int tx = tid & 31, ty = tid >> 5;
    const int h0 = bx * 32, d0 = by * 32;
    #pragma unroll
    for (int yy = 0; yy < 4; ++yy) {
      int dd = ty + yy * 8;
      tile[dd][tx] = W1[(768 + d0 + dd) * 768 + h0 + tx] - W1[(1536 + d0 + dd) * 768 + h0 + tx];
    }
    __syncthreads();
    #pragma unroll
    for (int yy = 0; yy < 4; ++yy) {
      int hh = ty + yy * 8;
      WbcT[(h0 + hh) * 768 + d0 + tx] = f2h(tile[tx][hh]);
    }

  } else if (b < 2144) {
    // ---- inverse norms, 1 wave per row ----
    const int rr = (b - 1952) * 4 + (tid >> 6);
    const int mat = rr >> 8, row = rr & 255;
    const float* src = (mat == 0) ? code : (mat == 1) ? nl : aug;
    const int l = tid & 63;
    float s = 0.f;
    #pragma unroll
    for (int t = 0; t < 12; ++t) { float v = src[row * 768 + l + t * 64]; s += v * v; }
    s = wave_sum(s);
    if (l == 0) ((mat == 0) ? invc : (mat == 1) ? invn : inva)[row] = rsqrtf(s);

  } else if (b < 2528) {
    // ---- verbatim output copies ----
    const int idx = (b - 2144) * 256 + tid;
    for (int t = idx; t < 196608; t += 384 * 256) {
      out[1 + t] = code[t];
      out[1 + 196608 + t] = nl[t];
    }

  } else {
    // ---- zero s_sum + acc ----
    const int idx = (b - 2528) * 256 + tid;
    ((float4*)s_sum)[idx] = make_float4(0.f, 0.f, 0.f, 0.f);
    if (b == 2528 && tid < 16) accv[tid] = 0.f;
  }
}

// ================= big pair kernel =================
// prod+lin2 [j,h] = sum_k code[j,k] * (nl[i,k]*Wd[k,h] + (Wb-Wc)[k,h])
// Occupancy model (r4/r6/r8 verified): unified VGPR+AGPR total/wave decides
// blocks/CU: r8 was 76+64=140 -> 3 waves/SIMD -> 1 block/CU (23%).
// Fix: (a) stageB self-contained (no 20-reg prefetch live across MFMA),
// (b) __launch_bounds__(512,4) caps total at 128 -> 2 blocks/CU; acc=64 AGPR
// leaves 64 VGPR (est. need ~55). Co-resident block's MFMA hides staging.
// grid 1536 = 6 h-tiles x 256 i; block 512 thr = 8 waves (4 row x 2 col), tile 256j x 128h
__global__ __launch_bounds__(512, 4) void k_pair(
    const unsigned short* __restrict__ code_f16, const unsigned short* __restrict__ nl_f16,
    const unsigned short* __restrict__ WdT, const unsigned short* __restrict__ WbcT,
    const unsigned short* __restrict__ lin1_f16,
    const float* __restrict__ b1, const float* __restrict__ W2,
    float* __restrict__ s_sum) {
  __shared__ __align__(16) unsigned short Alds[256 * 64];   // 32 KB
  __shared__ __align__(16) unsigned short Blds[128 * 64];   // 16 KB
  __shared__ float linb[128];
  __shared__ float w2s[128];

  const int tid = threadIdx.x;
  const int bid = blockIdx.x;
  const int ct = bid >> 8;        // 0..5; a dispatch generation shares ct -> WdT/WbcT slice L2-hot
  const int i  = bid & 255;
  const int h0 = ct << 7;

  if (tid < 128) {
    linb[tid] = (float)((const _Float16*)lin1_f16)[i * 768 + h0 + tid] + b1[h0 + tid];
    w2s[tid]  = W2[h0 + tid];
  }

  const int w = tid >> 6, lane = tid & 63;
  const int lr = lane & 15, g = lane >> 4;
  const int wr = (w >> 1) << 6;   // 0,64,128,192
  const int wc = (w & 1) << 6;    // 0,64
  const int c4 = tid & 7, rg = tid >> 3;  // staging: k-chunk / row-group

  f32x4 acc[4][4] = {};

  auto stage_A = [&](int kt) {  // code tile 256x64 via async global_load_lds, LDS linear
    const int k0 = kt << 6;
    #pragma unroll
    for (int q = 0; q < 4; ++q) {
      const int chunk = q * 512 + tid;
      const int row = chunk >> 3, c = chunk & 7;
      const unsigned short* src = code_f16 + row * 768 + k0 + ((c ^ (row & 7)) << 3);
      char* dst = (char*)Alds + (q * 512 + w * 64) * 16;  // wave-uniform base + lane*16
      gload_lds16(src, dst);
    }
  };

  // B' staging, self-contained per kt: loads+fma+write all inside the staging
  // phase (no registers live across the MFMA phase -> 2 blocks/CU possible).
  auto stageB = [&](int kt) {
    const int k0 = kt << 6;
    const uint4 nv  = *(const uint4*)(nl_f16 + i * 768 + k0 + (c4 << 3));
    const uint4 wv0 = *(const uint4*)(WdT  + (h0 + rg) * 768 + k0 + (c4 << 3));
    const uint4 bv0 = *(const uint4*)(WbcT + (h0 + rg) * 768 + k0 + (c4 << 3));
    const uint4 wv1 = *(const uint4*)(WdT  + (h0 + rg + 64) * 768 + k0 + (c4 << 3));
    const uint4 bv1 = *(const uint4*)(WbcT + (h0 + rg + 64) * 768 + k0 + (c4 << 3));
    uint4 p0, p1;
    asm("v_pk_fma_f16 %0, %1, %2, %3" : "=v"(p0.x) : "v"(nv.x), "v"(wv0.x), "v"(bv0.x));
    asm("v_pk_fma_f16 %0, %1, %2, %3" : "=v"(p0.y) : "v"(nv.y), "v"(wv0.y), "v"(bv0.y));
    asm("v_pk_fma_f16 %0, %1, %2, %3" : "=v"(p0.z) : "v"(nv.z), "v"(wv0.z), "v"(bv0.z));
    asm("v_pk_fma_f16 %0, %1, %2, %3" : "=v"(p0.w) : "v"(nv.w), "v"(wv0.w), "v"(bv0.w));
    asm("v_pk_fma_f16 %0, %1, %2, %3" : "=v"(p1.x) : "v"(nv.x), "v"(wv1.x), "v"(bv1.x));
    asm("v_pk_fma_f16 %0, %1, %2, %3" : "=v"(p1.y) : "v"(nv.y), "v"(wv1.y), "v"(bv1.y));
    asm("v_pk_fma_f16 %0, %1, %2, %3" : "=v"(p1.z) : "v"(nv.z), "v"(wv1.z), "v"(bv1.z));
    asm("v_pk_fma_f16 %0, %1, %2, %3" : "=v"(p1.w) : "v"(nv.w), "v"(wv1.w), "v"(bv1.w));
    const int r0 = rg, r1 = rg + 64;
    *(uint4*)((char*)Blds + r0 * 128 + ((c4 ^ (r0 & 7)) << 4)) = p0;
    *(uint4*)((char*)Blds + r1 * 128 + ((c4 ^ (r1 & 7)) << 4)) = p1;
  };

  for (int kt = 0; kt < 12; ++kt) {
    if (kt) __syncthreads();     // all reads of previous tile complete before overwrite
    stage_A(kt);                 // async gload_lds into Alds (in flight during stageB)
    stageB(kt);                  // B' loads -> pk_fma -> ds_write (self-contained)
    __syncthreads();             // staging visible; co-resident block's MFMA covers drain
    #pragma unroll
    for (int ks = 0; ks < 2; ++ks) {
      halfx8 bf[4];
      #pragma unroll
      for (int n = 0; n < 4; ++n) {
        const int row = wc + n * 16 + lr;
        bf[n] = *(const halfx8*)((const char*)Blds + row * 128 + (((ks * 4 + g) ^ (row & 7)) << 4));
      }
      #pragma unroll
      for (int m = 0; m < 4; ++m) {
        const int row = wr + m * 16 + lr;
        halfx8 af = *(const halfx8*)((const char*)Alds + row * 128 + (((ks * 4 + g) ^ (row & 7)) << 4));
        #pragma unroll
        for (int n = 0; n < 4; ++n)
          acc[m][n] = __builtin_amdgcn_mfma_f32_16x16x32_f16(af, bf[n], acc[m][n], 0, 0, 0);
      }
    }
  }

  // ---- epilogue: +lin1+b1 (lin2 folded into GEMM), tanh, *W2, h-reduce, atomic ----
  #pragma unroll
  for (int m = 0; m < 4; ++m) {
    #pragma unroll
    for (int reg = 0; reg < 4; ++reg) {
      const int rloc = wr + m * 16 + g * 4 + reg;   // j in 0..255
      float rs = 0.f;
      #pragma unroll
      for (int n = 0; n < 4; ++n) {
        const int cc = wc + n * 16 + lr;
        float x = acc[m][n][reg] + linb[cc];
        x = fminf(fmaxf(x, -15.f), 15.f);
        const float e = __expf(2.f * x);
        rs += __fdividef(e - 1.f, e + 1.f) * w2s[cc];
      }
      rs += __shfl_xor(rs, 1); rs += __shfl_xor(rs, 2);
      rs += __shfl_xor(rs, 4); rs += __shfl_xor(rs, 8);
      if (lr == 0) atomicAdd(&s_sum[i * 256 + rloc], rs);
    }
  }
}

// ================= fused losses =================
__global__ __launch_bounds__(256) void k_loss(const float* __restrict__ G,
    const float* __restrict__ invc, const float* __restrict__ invn, const float* __restrict__ inva,
    const float* __restrict__ s_sum, const float* __restrict__ b2, float* __restrict__ acc) {
  __shared__ float sred[4];
  __shared__ float dvals[3];
  const int t = threadIdx.x;
  if (blockIdx.x < 256) {
    const int i = blockIdx.x;
    const float* Snc = G;
    const float* Scc = G + 65536;
    const float* Snn = G + 131072;
    const float* Sca = G + 196608;
    const float* Sna = G + 262144;
    const float ici = invc[i], ini = invn[i];
    const float ict = invc[t], intt = invn[t], iat = inva[t];
    const float snc_it = Snc[i * 256 + t];
    const float snc_ti = Snc[t * 256 + i];
    const float e1 = snc_ti * ici * intt * INVT;
    const float e2 = (t == i) ? 0.f : 0.8f * INVT * Scc[i * 256 + t] * ici * ict;
    const float e3 = 0.1f * INVT * Sca[i * 256 + t] * ici * iat;
    const float f1 = snc_it * ini * ict * INVT;
    const float f2 = (t == i) ? 0.f : 0.8f * INVT * Snn[i * 256 + t] * ini * intt;
    const float f3 = 0.1f * INVT * Sna[i * 256 + t] * ini * iat;

    const float Mce = block_max(snc_it, sred);
    const float Mco = block_max(fmaxf(fmaxf(e1, e2), e3), sred);
    const float Mnl = block_max(fmaxf(fmaxf(f1, f2), f3), sred);
    const float Sce = block_sum(expf(snc_it - Mce), sred);
    const float Sco = block_sum(expf(e1 - Mco) + expf(e2 - Mco) + expf(e3 - Mco), sred);
    const float Snl = block_sum(expf(f1 - Mnl) + expf(f2 - Mnl) + expf(f3 - Mnl), sred);
    if (t == i) {
      dvals[0] = snc_it;
      dvals[1] = expf(e1 - Mco) + expf(e3 - Mco);
      dvals[2] = expf(f1 - Mnl) + expf(f3 - Mnl);
    }
    __syncthreads();
    if (t == 0) {
      atomicAdd(&acc[0], Mce + logf(Sce) - dvals[0]);
      atomicAdd(&acc[1], logf(Sco) - logf(dvals[1]));
      atomicAdd(&acc[2], logf(Snl) - logf(dvals[2]));
    }
  } else {
    const int r = (blockIdx.x - 256) * 256 + t;
    const int i = r >> 8, j = r & 255;
    const float s = s_sum[r] + b2[0];
    const float logit = 1.f / (1.f + expf(-s));
    const float pos = (i == j) ? logf(logit + EPSV) : 0.f;
    const float neg = (i == j) ? 0.f : logf(1.f - logit + EPSV);
    const float ps = block_sum(pos, sred);
    const float ns = block_sum(neg, sred);
    if (t == 0) { atomicAdd(&acc[3], ps); atomicAdd(&acc[4], ns); }
  }
}

// ================= final combine =================
__global__ void k_final(const float* __restrict__ acc, float* __restrict__ out) {
  if (threadIdx.x == 0 && blockIdx.x == 0) {
    const float lce = acc[0] * (1.f / 256.f);
    const float lclr = (acc[1] * (1.f / 256.f) + acc[2] * (1.f / 256.f)) * 0.5f;
    const float lcls = -(acc[4] * (1.f / (256.f * 255.f)) + acc[3] * (1.f / 256.f));
    out[0] = lce + 0.1f * lclr + lcls;
  }
}

extern "C" void kernel_launch(void* const* d_in, const int* in_sizes, int n_in,
                              void* d_out, int out_size, void* d_ws, size_t ws_size,
                              hipStream_t stream) {
  const float* code = (const float*)d_in[0];
  const float* nl   = (const float*)d_in[1];
  const float* aug  = (const float*)d_in[2];
  const float* W1   = (const float*)d_in[3];
  const float* b1   = (const float*)d_in[4];
  const float* W2   = (const float*)d_in[5];
  const float* b2   = (const float*)d_in[6];
  float* out = (float*)d_out;
  char* ws = (char*)d_ws;

  unsigned short* WdT      = (unsigned short*)(ws + 0);        // 1,179,648 B
  unsigned short* WbcT     = (unsigned short*)(ws + 1179648);  // 1,179,648 B
  unsigned short* code_f16 = (unsigned short*)(ws + 2359296);  // 393,216 B
  unsigned short* nl_f16   = (unsigned short*)(ws + 2752512);  // 393,216 B
  unsigned short* lin1_f16 = (unsigned short*)(ws + 3145728);  // 393,216 B
  float* G    = (float*)(ws + 3538944);                        // 1,310,720 B
  float* invc = (float*)(ws + 4849664);
  float* invn = (float*)(ws + 4850688);
  float* inva = (float*)(ws + 4851712);
  float* s_sum = (float*)(ws + 4852736);                       // 262,144 B
  float* acc   = (float*)(ws + 5114880);                       // 64 B  (total 5,114,944)

  k_prep<<<2592, 256, 0, stream>>>(code, nl, aug, W1, code_f16, nl_f16, WdT, WbcT,
                                   lin1_f16, invc, invn, inva, G, out, s_sum, acc);
  k_pair<<<1536, 512, 0, stream>>>(code_f16, nl_f16, WdT, WbcT, lin1_f16, b1, W2, s_sum);
  k_loss<<<512, 256, 0, stream>>>(G, invc, invn, inva, s_sum, b2, acc);
  k_final<<<1, 1, 0, stream>>>(acc, out);
}

// Round 12
// 238.230 us; speedup vs baseline: 3.0959x; 1.0030x over previous
//
#include <hip/hip_runtime.h>
#include <stdint.h>

#define EPSV 1e-5f
#define INVT (1.0f/0.03f)

typedef _Float16 halfx8 __attribute__((ext_vector_type(8)));
typedef float f32x4 __attribute__((ext_vector_type(4)));

__device__ __forceinline__ unsigned short f2h(float f) {
  _Float16 h = (_Float16)f;
  return __builtin_bit_cast(unsigned short, h);
}

__device__ __forceinline__ float wave_sum(float v) {
  #pragma unroll
  for (int m = 32; m; m >>= 1) v += __shfl_xor(v, m);
  return v;
}
__device__ __forceinline__ float wave_max(float v) {
  #pragma unroll
  for (int m = 32; m; m >>= 1) v = fmaxf(v, __shfl_xor(v, m));
  return v;
}
// block = 256 threads = 4 waves
__device__ __forceinline__ float block_sum(float v, float* sred) {
  v = wave_sum(v);
  __syncthreads();
  if ((threadIdx.x & 63) == 0) sred[threadIdx.x >> 6] = v;
  __syncthreads();
  return sred[0] + sred[1] + sred[2] + sred[3];
}
__device__ __forceinline__ float block_max(float v, float* sred) {
  v = wave_max(v);
  __syncthreads();
  if ((threadIdx.x & 63) == 0) sred[threadIdx.x >> 6] = v;
  __syncthreads();
  return fmaxf(fmaxf(sred[0], sred[1]), fmaxf(sred[2], sred[3]));
}

__device__ __forceinline__ void gload_lds16(const void* g, void* l) {
  __builtin_amdgcn_global_load_lds((__attribute__((address_space(1))) void*)g,
                                   (__attribute__((address_space(3))) void*)l, 16, 0, 0);
}

// ================= fused prep =================
// b ranges: [0,96) lin1 | [96,416) gram | [416,800) f16-conv | [800,1376) WdT
//           [1376,1952) WbcT | [1952,2144) norms | [2144,2528) copies | [2528,2592) zero
__global__ __launch_bounds__(256) void k_prep(
    const float* __restrict__ code, const float* __restrict__ nl, const float* __restrict__ aug,
    const float* __restrict__ W1,
    unsigned short* __restrict__ code_f16, unsigned short* __restrict__ nl_f16,
    unsigned short* __restrict__ WdT, unsigned short* __restrict__ WbcT,
    unsigned short* __restrict__ lin1_f16,
    float* __restrict__ invc, float* __restrict__ invn, float* __restrict__ inva,
    float* __restrict__ G,
    float* __restrict__ out, float* __restrict__ s_sum, float* __restrict__ accv) {
  __shared__ __align__(16) float smem[4112];
  const int b = blockIdx.x, tid = threadIdx.x;

  if (b < 96) {
    // ---- lin1 = nl@(Wa+Wc), fp32 accum, f16 store ----
    const int rt = b / 12, ct = b % 12;
    const int r0 = rt * 32, c0 = ct * 64;
    float* Xs = smem;          // 32*33
    float* Ws = smem + 1056;   // 32*64
    const int tx = tid & 15, ty = tid >> 4;
    float a[2][4] = {};
    for (int kt = 0; kt < 24; ++kt) {
      const int k0 = kt * 32;
      __syncthreads();
      #pragma unroll
      for (int q = 0; q < 4; ++q) {
        int e = q * 256 + tid;
        int row = e >> 5, k = e & 31;
        Xs[row * 33 + k] = nl[(r0 + row) * 768 + k0 + k];
      }
      #pragma unroll
      for (int q = 0; q < 8; ++q) {
        int e = q * 256 + tid;
        int k = e >> 6, c = e & 63;
        Ws[k * 64 + c] = W1[(k0 + k) * 768 + c0 + c] + W1[(1536 + k0 + k) * 768 + c0 + c];
      }
      __syncthreads();
      #pragma unroll
      for (int k = 0; k < 32; ++k) {
        float xa = Xs[ty * 33 + k], xb = Xs[(ty + 16) * 33 + k];
        float w0 = Ws[k * 64 + tx], w1 = Ws[k * 64 + tx + 16];
        float w2 = Ws[k * 64 + tx + 32], w3 = Ws[k * 64 + tx + 48];
        a[0][0] += xa * w0; a[0][1] += xa * w1; a[0][2] += xa * w2; a[0][3] += xa * w3;
        a[1][0] += xb * w0; a[1][1] += xb * w1; a[1][2] += xb * w2; a[1][3] += xb * w3;
      }
    }
    #pragma unroll
    for (int dy = 0; dy < 2; ++dy)
      #pragma unroll
      for (int m = 0; m < 4; ++m)
        lin1_f16[(r0 + ty + dy * 16) * 768 + c0 + tx + m * 16] = f2h(a[dy][m]);

  } else if (b < 416) {
    // ---- 5 Gram matrices (fp32) ----
    const int bb = b - 96;
    const int mat = bb >> 6;
    const int tile = bb & 63;
    const int y0 = (tile >> 3) * 32, x0 = (tile & 7) * 32;
    const float* X; const float* Y;
    if (mat == 0)      { X = nl;   Y = code; }
    else if (mat == 1) { X = code; Y = code; }
    else if (mat == 2) { X = nl;   Y = nl;   }
    else if (mat == 3) { X = code; Y = aug;  }
    else               { X = nl;   Y = aug;  }
    float* outg = G + mat * 65536;
    float* Xs = smem;           // 32*64
    float* Ys = smem + 2048;    // 32*64
    const int tx = tid & 15, ty = tid >> 4;
    float a00 = 0, a01 = 0, a10 = 0, a11 = 0;
    for (int kt = 0; kt < 12; ++kt) {
      const int k0 = kt * 64;
      __syncthreads();
      #pragma unroll
      for (int q = 0; q < 2; ++q) {
        int chunk = q * 256 + tid;
        int row = chunk >> 4, c4 = chunk & 15;
        float4 xv = *(const float4*)(X + (y0 + row) * 768 + k0 + c4 * 4);
        float4 yv = *(const float4*)(Y + (x0 + row) * 768 + k0 + c4 * 4);
        *(float4*)(Xs + row * 64 + ((c4 ^ (row & 15)) << 2)) = xv;
        *(float4*)(Ys + row * 64 + ((c4 ^ (row & 15)) << 2)) = yv;
      }
      __syncthreads();
      #pragma unroll
      for (int c4 = 0; c4 < 16; ++c4) {
        float4 xa = *(const float4*)(Xs + ty * 64 + ((c4 ^ ty) << 2));
        float4 xb = *(const float4*)(Xs + (ty + 16) * 64 + ((c4 ^ ty) << 2));
        float4 ya = *(const float4*)(Ys + tx * 64 + ((c4 ^ tx) << 2));
        float4 yb = *(const float4*)(Ys + (tx + 16) * 64 + ((c4 ^ tx) << 2));
        a00 += xa.x * ya.x + xa.y * ya.y + xa.z * ya.z + xa.w * ya.w;
        a01 += xa.x * yb.x + xa.y * yb.y + xa.z * yb.z + xa.w * yb.w;
        a10 += xb.x * ya.x + xb.y * ya.y + xb.z * ya.z + xb.w * ya.w;
        a11 += xb.x * yb.x + xb.y * yb.y + xb.z * yb.z + xb.w * yb.w;
      }
    }
    outg[(y0 + ty) * 256 + x0 + tx] = a00;
    outg[(y0 + ty) * 256 + x0 + tx + 16] = a01;
    outg[(y0 + ty + 16) * 256 + x0 + tx] = a10;
    outg[(y0 + ty + 16) * 256 + x0 + tx + 16] = a11;

  } else if (b < 800) {
    // ---- fp32 -> f16 of code / nl ----
    const int idx = (b - 416) * 256 + tid;
    if (idx < 49152) {
      float4 v = ((const float4*)code)[idx];
      ushort4 o; o.x = f2h(v.x); o.y = f2h(v.y); o.z = f2h(v.z); o.w = f2h(v.w);
      ((ushort4*)code_f16)[idx] = o;
    } else {
      const int q = idx - 49152;
      float4 v = ((const float4*)nl)[q];
      ushort4 o; o.x = f2h(v.x); o.y = f2h(v.y); o.z = f2h(v.z); o.w = f2h(v.w);
      ((ushort4*)nl_f16)[q] = o;
    }

  } else if (b < 1376) {
    // ---- WdT[h][d] = f16(W1[2304+d][h]) ----
    float (*tile)[33] = (float(*)[33])smem;
    const int bb = b - 800;
    const int bx = bb % 24, by = bb / 24;
    const int tx = tid & 31, ty = tid >> 5;
    const int h0 = bx * 32, d0 = by * 32;
    #pragma unroll
    for (int yy = 0; yy < 4; ++yy) {
      int dd = ty + yy * 8;
      tile[dd][tx] = W1[(2304 + d0 + dd) * 768 + h0 + tx];
    }
    __syncthreads();
    #pragma unroll
    for (int yy = 0; yy < 4; ++yy) {
      int hh = ty + yy * 8;
      WdT[(h0 + hh) * 768 + d0 + tx] = f2h(tile[tx][hh]);
    }

  } else if (b < 1952) {
    // ---- WbcT[h][d] = f16(W1[768+d][h] - W1[1536+d][h]) ----
    float (*tile)[33] = (float(*)[33])smem;
    const int bb = b - 1376;
    const int bx = bb % 24, by = bb / 24;
    const int tx = tid & 31, ty = tid >> 5;
    const int h0 = bx * 32, d0 = by * 32;
    #pragma unroll
    for (int yy = 0; yy < 4; ++yy) {
      int dd = ty + yy * 8;
      tile[dd][tx] = W1[(768 + d0 + dd) * 768 + h0 + tx] - W1[(1536 + d0 + dd) * 768 + h0 + tx];
    }
    __syncthreads();
    #pragma unroll
    for (int yy = 0; yy < 4; ++yy) {
      int hh = ty + yy * 8;
      WbcT[(h0 + hh) * 768 + d0 + tx] = f2h(tile[tx][hh]);
    }

  } else if (b < 2144) {
    // ---- inverse norms, 1 wave per row ----
    const int rr = (b - 1952) * 4 + (tid >> 6);
    const int mat = rr >> 8, row = rr & 255;
    const float* src = (mat == 0) ? code : (mat == 1) ? nl : aug;
    const int l = tid & 63;
    float s = 0.f;
    #pragma unroll
    for (int t = 0; t < 12; ++t) { float v = src[row * 768 + l + t * 64]; s += v * v; }
    s = wave_sum(s);
    if (l == 0) ((mat == 0) ? invc : (mat == 1) ? invn : inva)[row] = rsqrtf(s);

  } else if (b < 2528) {
    // ---- verbatim output copies ----
    const int idx = (b - 2144) * 256 + tid;
    for (int t = idx; t < 196608; t += 384 * 256) {
      out[1 + t] = code[t];
      out[1 + 196608 + t] = nl[t];
    }

  } else {
    // ---- zero s_sum + acc ----
    const int idx = (b - 2528) * 256 + tid;
    ((float4*)s_sum)[idx] = make_float4(0.f, 0.f, 0.f, 0.f);
    if (b == 2528 && tid < 16) accv[tid] = 0.f;
  }
}

// ================= big pair kernel =================
// prod+lin2 [j,h] = sum_k code[j,k] * (nl[i,k]*Wd[k,h] + (Wb-Wc)[k,h])
// Occupancy model (r4/r6/r8/r9 verified): unified VGPR+AGPR total/wave decides
// blocks/CU. (512,4) caps total at 128 = 64 VGPR + 64 acc -> 2 blocks/CU (r9: 39%).
// r9 counter lesson: 512 atomics/block (2 waves per j) caused s_sum cacheline
// bouncing across XCDs -> WRITE_SIZE 48.6 MB. Fix: LDS pre-reduction (part[2][256]),
// then 256 single atomics/block.
// grid 1536 = 6 h-tiles x 256 i; block 512 thr = 8 waves (4 row x 2 col), tile 256j x 128h
__global__ __launch_bounds__(512, 4) void k_pair(
    const unsigned short* __restrict__ code_f16, const unsigned short* __restrict__ nl_f16,
    const unsigned short* __restrict__ WdT, const unsigned short* __restrict__ WbcT,
    const unsigned short* __restrict__ lin1_f16,
    const float* __restrict__ b1, const float* __restrict__ W2,
    float* __restrict__ s_sum) {
  __shared__ __align__(16) unsigned short Alds[256 * 64];   // 32 KB
  __shared__ __align__(16) unsigned short Blds[128 * 64];   // 16 KB
  __shared__ float linb[128];
  __shared__ float w2s[128];
  __shared__ float part[2][256];                            // 2 KB epilogue reduce

  const int tid = threadIdx.x;
  const int bid = blockIdx.x;
  const int ct = bid >> 8;        // 0..5; a dispatch generation shares ct -> WdT/WbcT slice L2-hot
  const int i  = bid & 255;
  const int h0 = ct << 7;

  if (tid < 128) {
    linb[tid] = (float)((const _Float16*)lin1_f16)[i * 768 + h0 + tid] + b1[h0 + tid];
    w2s[tid]  = W2[h0 + tid];
  }

  const int w = tid >> 6, lane = tid & 63;
  const int lr = lane & 15, g = lane >> 4;
  const int wr = (w >> 1) << 6;   // 0,64,128,192
  const int wcIdx = w & 1;
  const int wc = wcIdx << 6;      // 0,64
  const int c4 = tid & 7, rg = tid >> 3;  // staging: k-chunk / row-group

  f32x4 acc[4][4] = {};

  auto stage_A = [&](int kt) {  // code tile 256x64 via async global_load_lds, LDS linear
    const int k0 = kt << 6;
    #pragma unroll
    for (int q = 0; q < 4; ++q) {
      const int chunk = q * 512 + tid;
      const int row = chunk >> 3, c = chunk & 7;
      const unsigned short* src = code_f16 + row * 768 + k0 + ((c ^ (row & 7)) << 3);
      char* dst = (char*)Alds + (q * 512 + w * 64) * 16;  // wave-uniform base + lane*16
      gload_lds16(src, dst);
    }
  };

  // B' staging, self-contained per kt: loads+fma+write all inside the staging
  // phase (no registers live across the MFMA phase -> 2 blocks/CU possible).
  auto stageB = [&](int kt) {
    const int k0 = kt << 6;
    const uint4 nv  = *(const uint4*)(nl_f16 + i * 768 + k0 + (c4 << 3));
    const uint4 wv0 = *(const uint4*)(WdT  + (h0 + rg) * 768 + k0 + (c4 << 3));
    const uint4 bv0 = *(const uint4*)(WbcT + (h0 + rg) * 768 + k0 + (c4 << 3));
    const uint4 wv1 = *(const uint4*)(WdT  + (h0 + rg + 64) * 768 + k0 + (c4 << 3));
    const uint4 bv1 = *(const uint4*)(WbcT + (h0 + rg + 64) * 768 + k0 + (c4 << 3));
    uint4 p0, p1;
    asm("v_pk_fma_f16 %0, %1, %2, %3" : "=v"(p0.x) : "v"(nv.x), "v"(wv0.x), "v"(bv0.x));
    asm("v_pk_fma_f16 %0, %1, %2, %3" : "=v"(p0.y) : "v"(nv.y), "v"(wv0.y), "v"(bv0.y));
    asm("v_pk_fma_f16 %0, %1, %2, %3" : "=v"(p0.z) : "v"(nv.z), "v"(wv0.z), "v"(bv0.z));
    asm("v_pk_fma_f16 %0, %1, %2, %3" : "=v"(p0.w) : "v"(nv.w), "v"(wv0.w), "v"(bv0.w));
    asm("v_pk_fma_f16 %0, %1, %2, %3" : "=v"(p1.x) : "v"(nv.x), "v"(wv1.x), "v"(bv1.x));
    asm("v_pk_fma_f16 %0, %1, %2, %3" : "=v"(p1.y) : "v"(nv.y), "v"(wv1.y), "v"(bv1.y));
    asm("v_pk_fma_f16 %0, %1, %2, %3" : "=v"(p1.z) : "v"(nv.z), "v"(wv1.z), "v"(bv1.z));
    asm("v_pk_fma_f16 %0, %1, %2, %3" : "=v"(p1.w) : "v"(nv.w), "v"(wv1.w), "v"(bv1.w));
    const int r0 = rg, r1 = rg + 64;
    *(uint4*)((char*)Blds + r0 * 128 + ((c4 ^ (r0 & 7)) << 4)) = p0;
    *(uint4*)((char*)Blds + r1 * 128 + ((c4 ^ (r1 & 7)) << 4)) = p1;
  };

  for (int kt = 0; kt < 12; ++kt) {
    if (kt) __syncthreads();     // all reads of previous tile complete before overwrite
    stage_A(kt);                 // async gload_lds into Alds (in flight during stageB)
    stageB(kt);                  // B' loads -> pk_fma -> ds_write (self-contained)
    __syncthreads();             // staging visible; co-resident block's MFMA covers drain
    #pragma unroll
    for (int ks = 0; ks < 2; ++ks) {
      halfx8 bf[4];
      #pragma unroll
      for (int n = 0; n < 4; ++n) {
        const int row = wc + n * 16 + lr;
        bf[n] = *(const halfx8*)((const char*)Blds + row * 128 + (((ks * 4 + g) ^ (row & 7)) << 4));
      }
      #pragma unroll
      for (int m = 0; m < 4; ++m) {
        const int row = wr + m * 16 + lr;
        halfx8 af = *(const halfx8*)((const char*)Alds + row * 128 + (((ks * 4 + g) ^ (row & 7)) << 4));
        #pragma unroll
        for (int n = 0; n < 4; ++n)
          acc[m][n] = __builtin_amdgcn_mfma_f32_16x16x32_f16(af, bf[n], acc[m][n], 0, 0, 0);
      }
    }
  }

  // ---- epilogue: +lin1+b1 (lin2 folded into GEMM), tanh, *W2, h-reduce ----
  // Per-wave partials into part[wcIdx][j] (each entry written exactly once),
  // then ONE atomic per j: halves atomic count and kills same-address contention.
  #pragma unroll
  for (int m = 0; m < 4; ++m) {
    #pragma unroll
    for (int reg = 0; reg < 4; ++reg) {
      const int rloc = wr + m * 16 + g * 4 + reg;   // j in 0..255
      float rs = 0.f;
      #pragma unroll
      for (int n = 0; n < 4; ++n) {
        const int cc = wc + n * 16 + lr;
        float x = acc[m][n][reg] + linb[cc];
        x = fminf(fmaxf(x, -15.f), 15.f);
        const float e = __expf(2.f * x);
        rs += __fdividef(e - 1.f, e + 1.f) * w2s[cc];
      }
      rs += __shfl_xor(rs, 1); rs += __shfl_xor(rs, 2);
      rs += __shfl_xor(rs, 4); rs += __shfl_xor(rs, 8);
      if (lr == 0) part[wcIdx][rloc] = rs;
    }
  }
  __syncthreads();
  if (tid < 256) atomicAdd(&s_sum[i * 256 + tid], part[0][tid] + part[1][tid]);
}

// ================= fused losses =================
__global__ __launch_bounds__(256) void k_loss(const float* __restrict__ G,
    const float* __restrict__ invc, const float* __restrict__ invn, const float* __restrict__ inva,
    const float* __restrict__ s_sum, const float* __restrict__ b2, float* __restrict__ acc) {
  __shared__ float sred[4];
  __shared__ float dvals[3];
  const int t = threadIdx.x;
  if (blockIdx.x < 256) {
    const int i = blockIdx.x;
    const float* Snc = G;
    const float* Scc = G + 65536;
    const float* Snn = G + 131072;
    const float* Sca = G + 196608;
    const float* Sna = G + 262144;
    const float ici = invc[i], ini = invn[i];
    const float ict = invc[t], intt = invn[t], iat = inva[t];
    const float snc_it = Snc[i * 256 + t];
    const float snc_ti = Snc[t * 256 + i];
    const float e1 = snc_ti * ici * intt * INVT;
    const float e2 = (t == i) ? 0.f : 0.8f * INVT * Scc[i * 256 + t] * ici * ict;
    const float e3 = 0.1f * INVT * Sca[i * 256 + t] * ici * iat;
    const float f1 = snc_it * ini * ict * INVT;
    const float f2 = (t == i) ? 0.f : 0.8f * INVT * Snn[i * 256 + t] * ini * intt;
    const float f3 = 0.1f * INVT * Sna[i * 256 + t] * ini * iat;

    const float Mce = block_max(snc_it, sred);
    const float Mco = block_max(fmaxf(fmaxf(e1, e2), e3), sred);
    const float Mnl = block_max(fmaxf(fmaxf(f1, f2), f3), sred);
    const float Sce = block_sum(expf(snc_it - Mce), sred);
    const float Sco = block_sum(expf(e1 - Mco) + expf(e2 - Mco) + expf(e3 - Mco), sred);
    const float Snl = block_sum(expf(f1 - Mnl) + expf(f2 - Mnl) + expf(f3 - Mnl), sred);
    if (t == i) {
      dvals[0] = snc_it;
      dvals[1] = expf(e1 - Mco) + expf(e3 - Mco);
      dvals[2] = expf(f1 - Mnl) + expf(f3 - Mnl);
    }
    __syncthreads();
    if (t == 0) {
      atomicAdd(&acc[0], Mce + logf(Sce) - dvals[0]);
      atomicAdd(&acc[1], logf(Sco) - logf(dvals[1]));
      atomicAdd(&acc[2], logf(Snl) - logf(dvals[2]));
    }
  } else {
    const int r = (blockIdx.x - 256) * 256 + t;
    const int i = r >> 8, j = r & 255;
    const float s = s_sum[r] + b2[0];
    const float logit = 1.f / (1.f + expf(-s));
    const float pos = (i == j) ? logf(logit + EPSV) : 0.f;
    const float neg = (i == j) ? 0.f : logf(1.f - logit + EPSV);
    const float ps = block_sum(pos, sred);
    const float ns = block_sum(neg, sred);
    if (t == 0) { atomicAdd(&acc[3], ps); atomicAdd(&acc[4], ns); }
  }
}

// ================= final combine =================
__global__ void k_final(const float* __restrict__ acc, float* __restrict__ out) {
  if (threadIdx.x == 0 && blockIdx.x == 0) {
    const float lce = acc[0] * (1.f / 256.f);
    const float lclr = (acc[1] * (1.f / 256.f) + acc[2] * (1.f / 256.f)) * 0.5f;
    const float lcls = -(acc[4] * (1.f / (256.f * 255.f)) + acc[3] * (1.f / 256.f));
    out[0] = lce + 0.1f * lclr + lcls;
  }
}

extern "C" void kernel_launch(void* const* d_in, const int* in_sizes, int n_in,
                              void* d_out, int out_size, void* d_ws, size_t ws_size,
                              hipStream_t stream) {
  const float* code = (const float*)d_in[0];
  const float* nl   = (const float*)d_in[1];
  const float* aug  = (const float*)d_in[2];
  const float* W1   = (const float*)d_in[3];
  const float* b1   = (const float*)d_in[4];
  const float* W2   = (const float*)d_in[5];
  const float* b2   = (const float*)d_in[6];
  float* out = (float*)d_out;
  char* ws = (char*)d_ws;

  unsigned short* WdT      = (unsigned short*)(ws + 0);        // 1,179,648 B
  unsigned short* WbcT     = (unsigned short*)(ws + 1179648);  // 1,179,648 B
  unsigned short* code_f16 = (unsigned short*)(ws + 2359296);  // 393,216 B
  unsigned short* nl_f16   = (unsigned short*)(ws + 2752512);  // 393,216 B
  unsigned short* lin1_f16 = (unsigned short*)(ws + 3145728);  // 393,216 B
  float* G    = (float*)(ws + 3538944);                        // 1,310,720 B
  float* invc = (float*)(ws + 4849664);
  float* invn = (float*)(ws + 4850688);
  float* inva = (float*)(ws + 4851712);
  float* s_sum = (float*)(ws + 4852736);                       // 262,144 B
  float* acc   = (float*)(ws + 5114880);                       // 64 B  (total 5,114,944)

  k_prep<<<2592, 256, 0, stream>>>(code, nl, aug, W1, code_f16, nl_f16, WdT, WbcT,
                                   lin1_f16, invc, invn, inva, G, out, s_sum, acc);
  k_pair<<<1536, 512, 0, stream>>>(code_f16, nl_f16, WdT, WbcT, lin1_f16, b1, W2, s_sum);
  k_loss<<<512, 256, 0, stream>>>(G, invc, invn, inva, s_sum, b2, acc);
  k_final<<<1, 1, 0, stream>>>(acc, out);
}

// Round 13
// 229.648 us; speedup vs baseline: 3.2116x; 1.0374x over previous
//
#include <hip/hip_runtime.h>
#include <stdint.h>

#define EPSV 1e-5f
#define INVT (1.0f/0.03f)

typedef _Float16 halfx8 __attribute__((ext_vector_type(8)));
typedef float f32x4 __attribute__((ext_vector_type(4)));

__device__ __forceinline__ unsigned short f2h(float f) {
  _Float16 h = (_Float16)f;
  return __builtin_bit_cast(unsigned short, h);
}

__device__ __forceinline__ float wave_sum(float v) {
  #pragma unroll
  for (int m = 32; m; m >>= 1) v += __shfl_xor(v, m);
  return v;
}
__device__ __forceinline__ float wave_max(float v) {
  #pragma unroll
  for (int m = 32; m; m >>= 1) v = fmaxf(v, __shfl_xor(v, m));
  return v;
}
// block = 256 threads = 4 waves
__device__ __forceinline__ float block_sum(float v, float* sred) {
  v = wave_sum(v);
  __syncthreads();
  if ((threadIdx.x & 63) == 0) sred[threadIdx.x >> 6] = v;
  __syncthreads();
  return sred[0] + sred[1] + sred[2] + sred[3];
}
__device__ __forceinline__ float block_max(float v, float* sred) {
  v = wave_max(v);
  __syncthreads();
  if ((threadIdx.x & 63) == 0) sred[threadIdx.x >> 6] = v;
  __syncthreads();
  return fmaxf(fmaxf(sred[0], sred[1]), fmaxf(sred[2], sred[3]));
}

__device__ __forceinline__ void gload_lds16(const void* g, void* l) {
  __builtin_amdgcn_global_load_lds((__attribute__((address_space(1))) void*)g,
                                   (__attribute__((address_space(3))) void*)l, 16, 0, 0);
}

// ================= fused prep =================
// b ranges: [0,96) lin1 | [96,416) gram | [416,800) f16-conv | [800,1376) WdT
//           [1376,1952) WbcT | [1952,2144) norms | [2144,2528) copies | [2528,2592) zero
__global__ __launch_bounds__(256) void k_prep(
    const float* __restrict__ code, const float* __restrict__ nl, const float* __restrict__ aug,
    const float* __restrict__ W1,
    unsigned short* __restrict__ code_f16, unsigned short* __restrict__ nl_f16,
    unsigned short* __restrict__ WdT, unsigned short* __restrict__ WbcT,
    unsigned short* __restrict__ lin1_f16,
    float* __restrict__ invc, float* __restrict__ invn, float* __restrict__ inva,
    float* __restrict__ G,
    float* __restrict__ out, float* __restrict__ s_sum, float* __restrict__ accv) {
  __shared__ __align__(16) float smem[4112];
  const int b = blockIdx.x, tid = threadIdx.x;

  if (b < 96) {
    // ---- lin1 = nl@(Wa+Wc), fp32 accum, f16 store ----
    const int rt = b / 12, ct = b % 12;
    const int r0 = rt * 32, c0 = ct * 64;
    float* Xs = smem;          // 32*33
    float* Ws = smem + 1056;   // 32*64
    const int tx = tid & 15, ty = tid >> 4;
    float a[2][4] = {};
    for (int kt = 0; kt < 24; ++kt) {
      const int k0 = kt * 32;
      __syncthreads();
      #pragma unroll
      for (int q = 0; q < 4; ++q) {
        int e = q * 256 + tid;
        int row = e >> 5, k = e & 31;
        Xs[row * 33 + k] = nl[(r0 + row) * 768 + k0 + k];
      }
      #pragma unroll
      for (int q = 0; q < 8; ++q) {
        int e = q * 256 + tid;
        int k = e >> 6, c = e & 63;
        Ws[k * 64 + c] = W1[(k0 + k) * 768 + c0 + c] + W1[(1536 + k0 + k) * 768 + c0 + c];
      }
      __syncthreads();
      #pragma unroll
      for (int k = 0; k < 32; ++k) {
        float xa = Xs[ty * 33 + k], xb = Xs[(ty + 16) * 33 + k];
        float w0 = Ws[k * 64 + tx], w1 = Ws[k * 64 + tx + 16];
        float w2 = Ws[k * 64 + tx + 32], w3 = Ws[k * 64 + tx + 48];
        a[0][0] += xa * w0; a[0][1] += xa * w1; a[0][2] += xa * w2; a[0][3] += xa * w3;
        a[1][0] += xb * w0; a[1][1] += xb * w1; a[1][2] += xb * w2; a[1][3] += xb * w3;
      }
    }
    #pragma unroll
    for (int dy = 0; dy < 2; ++dy)
      #pragma unroll
      for (int m = 0; m < 4; ++m)
        lin1_f16[(r0 + ty + dy * 16) * 768 + c0 + tx + m * 16] = f2h(a[dy][m]);

  } else if (b < 416) {
    // ---- 5 Gram matrices (fp32) ----
    const int bb = b - 96;
    const int mat = bb >> 6;
    const int tile = bb & 63;
    const int y0 = (tile >> 3) * 32, x0 = (tile & 7) * 32;
    const float* X; const float* Y;
    if (mat == 0)      { X = nl;   Y = code; }
    else if (mat == 1) { X = code; Y = code; }
    else if (mat == 2) { X = nl;   Y = nl;   }
    else if (mat == 3) { X = code; Y = aug;  }
    else               { X = nl;   Y = aug;  }
    float* outg = G + mat * 65536;
    float* Xs = smem;           // 32*64
    float* Ys = smem + 2048;    // 32*64
    const int tx = tid & 15, ty = tid >> 4;
    float a00 = 0, a01 = 0, a10 = 0, a11 = 0;
    for (int kt = 0; kt < 12; ++kt) {
      const int k0 = kt * 64;
      __syncthreads();
      #pragma unroll
      for (int q = 0; q < 2; ++q) {
        int chunk = q * 256 + tid;
        int row = chunk >> 4, c4 = chunk & 15;
        float4 xv = *(const float4*)(X + (y0 + row) * 768 + k0 + c4 * 4);
        float4 yv = *(const float4*)(Y + (x0 + row) * 768 + k0 + c4 * 4);
        *(float4*)(Xs + row * 64 + ((c4 ^ (row & 15)) << 2)) = xv;
        *(float4*)(Ys + row * 64 + ((c4 ^ (row & 15)) << 2)) = yv;
      }
      __syncthreads();
      #pragma unroll
      for (int c4 = 0; c4 < 16; ++c4) {
        float4 xa = *(const float4*)(Xs + ty * 64 + ((c4 ^ ty) << 2));
        float4 xb = *(const float4*)(Xs + (ty + 16) * 64 + ((c4 ^ ty) << 2));
        float4 ya = *(const float4*)(Ys + tx * 64 + ((c4 ^ tx) << 2));
        float4 yb = *(const float4*)(Ys + (tx + 16) * 64 + ((c4 ^ tx) << 2));
        a00 += xa.x * ya.x + xa.y * ya.y + xa.z * ya.z + xa.w * ya.w;
        a01 += xa.x * yb.x + xa.y * yb.y + xa.z * yb.z + xa.w * yb.w;
        a10 += xb.x * ya.x + xb.y * ya.y + xb.z * ya.z + xb.w * ya.w;
        a11 += xb.x * yb.x + xb.y * yb.y + xb.z * yb.z + xb.w * yb.w;
      }
    }
    outg[(y0 + ty) * 256 + x0 + tx] = a00;
    outg[(y0 + ty) * 256 + x0 + tx + 16] = a01;
    outg[(y0 + ty + 16) * 256 + x0 + tx] = a10;
    outg[(y0 + ty + 16) * 256 + x0 + tx + 16] = a11;

  } else if (b < 800) {
    // ---- fp32 -> f16 of code / nl ----
    const int idx = (b - 416) * 256 + tid;
    if (idx < 49152) {
      float4 v = ((const float4*)code)[idx];
      ushort4 o; o.x = f2h(v.x); o.y = f2h(v.y); o.z = f2h(v.z); o.w = f2h(v.w);
      ((ushort4*)code_f16)[idx] = o;
    } else {
      const int q = idx - 49152;
      float4 v = ((const float4*)nl)[q];
      ushort4 o; o.x = f2h(v.x); o.y = f2h(v.y); o.z = f2h(v.z); o.w = f2h(v.w);
      ((ushort4*)nl_f16)[q] = o;
    }

  } else if (b < 1376) {
    // ---- WdT[h][d] = f16(W1[2304+d][h]) ----
    float (*tile)[33] = (float(*)[33])smem;
    const int bb = b - 800;
    const int bx = bb % 24, by = bb / 24;
    const int tx = tid & 31, ty = tid >> 5;
    const int h0 = bx * 32, d0 = by * 32;
    #pragma unroll
    for (int yy = 0; yy < 4; ++yy) {
      int dd = ty + yy * 8;
      tile[dd][tx] = W1[(2304 + d0 + dd) * 768 + h0 + tx];
    }
    __syncthreads();
    #pragma unroll
    for (int yy = 0; yy < 4; ++yy) {
      int hh = ty + yy * 8;
      WdT[(h0 + hh) * 768 + d0 + tx] = f2h(tile[tx][hh]);
    }

  } else if (b < 1952) {
    // ---- WbcT[h][d] = f16(W1[768+d][h] - W1[1536+d][h]) ----
    float (*tile)[33] = (float(*)[33])smem;
    const int bb = b - 1376;
    const int bx = bb % 24, by = bb / 24;
    const int tx = tid & 31, ty = tid >> 5;
    const int h0 = bx * 32, d0 = by * 32;
    #pragma unroll
    for (int yy = 0; yy < 4; ++yy) {
      int dd = ty + yy * 8;
      tile[dd][tx] = W1[(768 + d0 + dd) * 768 + h0 + tx] - W1[(1536 + d0 + dd) * 768 + h0 + tx];
    }
    __syncthreads();
    #pragma unroll
    for (int yy = 0; yy < 4; ++yy) {
      int hh = ty + yy * 8;
      WbcT[(h0 + hh) * 768 + d0 + tx] = f2h(tile[tx][hh]);
    }

  } else if (b < 2144) {
    // ---- inverse norms, 1 wave per row ----
    const int rr = (b - 1952) * 4 + (tid >> 6);
    const int mat = rr >> 8, row = rr & 255;
    const float* src = (mat == 0) ? code : (mat == 1) ? nl : aug;
    const int l = tid & 63;
    float s = 0.f;
    #pragma unroll
    for (int t = 0; t < 12; ++t) { float v = src[row * 768 + l + t * 64]; s += v * v; }
    s = wave_sum(s);
    if (l == 0) ((mat == 0) ? invc : (mat == 1) ? invn : inva)[row] = rsqrtf(s);

  } else if (b < 2528) {
    // ---- verbatim output copies ----
    const int idx = (b - 2144) * 256 + tid;
    for (int t = idx; t < 196608; t += 384 * 256) {
      out[1 + t] = code[t];
      out[1 + 196608 + t] = nl[t];
    }

  } else {
    // ---- zero s_sum + acc ----
    const int idx = (b - 2528) * 256 + tid;
    ((float4*)s_sum)[idx] = make_float4(0.f, 0.f, 0.f, 0.f);
    if (b == 2528 && tid < 16) accv[tid] = 0.f;
  }
}

// ================= big pair kernel =================
// prod+lin2 [j,h] = sum_k code[j,k] * (nl[i,k]*Wd[k,h] + (Wb-Wc)[k,h])
// r12 counters: VALUBusy 38% > MfmaUtil 26% -> staging VALU dominates. Fix:
// each block computes TWO i values on a 128j x 128h tile; WdT/WbcT loads and
// code A-tile amortize across both i (global loads/unit 5->3, gload_lds 4->2),
// MFMA per block unchanged. Occupancy equation preserved: per-wave 64x64 tile
// -> acc[4][4]=64 AGPR + ~64 VGPR = 128 = (512,4) cap -> 2 blocks/CU.
// LDS: 16K A + 32K B[2] + 3.5K = 52.7 KB -> 105 KB/CU for 2 blocks.
// grid 1536 = 6 ct x 2 jt x 128 ipair; block 512 thr = 8 waves (2i x 2jr x 2hc).
__global__ __launch_bounds__(512, 4) void k_pair(
    const unsigned short* __restrict__ code_f16, const unsigned short* __restrict__ nl_f16,
    const unsigned short* __restrict__ WdT, const unsigned short* __restrict__ WbcT,
    const unsigned short* __restrict__ lin1_f16,
    const float* __restrict__ b1, const float* __restrict__ W2,
    float* __restrict__ s_sum) {
  __shared__ __align__(16) unsigned short Alds[128 * 64];      // 16 KB (code, shared by both i)
  __shared__ __align__(16) unsigned short Blds[2][128 * 64];   // 32 KB (B' per i)
  __shared__ float linb[2][128];
  __shared__ float w2s[128];
  __shared__ float part[2][2][128];                            // epilogue reduce

  const int tid = threadIdx.x;
  const int bid = blockIdx.x;
  const int ct = bid >> 8;        // 0..5; generation shares ct -> WdT/WbcT slice L2-hot
  const int r  = bid & 255;
  const int jt = r >> 7;          // 0..1 j-tile
  const int ip = r & 127;         // i-pair
  const int i0 = ip << 1;
  const int h0 = ct << 7;
  const int j0 = jt << 7;

  if (tid < 256) {
    const int ihh = tid >> 7, hh = tid & 127;
    linb[ihh][hh] = (float)((const _Float16*)lin1_f16)[(i0 + ihh) * 768 + h0 + hh] + b1[h0 + hh];
  }
  if (tid < 128) w2s[tid] = W2[h0 + tid];

  const int w = tid >> 6, lane = tid & 63;
  const int lr = lane & 15, g = lane >> 4;
  const int ih = w >> 2;            // which i this wave computes
  const int wq = w & 3;
  const int wr = (wq >> 1) << 6;    // j offset 0/64
  const int wcIdx = wq & 1;
  const int wc = wcIdx << 6;        // h offset 0/64
  const int c4 = tid & 7, rg = tid >> 3;  // staging: k-chunk / row-group (rg in [0,64))

  f32x4 acc[4][4] = {};

  auto stage_A = [&](int kt) {  // code tile 128x64 via async global_load_lds, LDS linear
    const int k0 = kt << 6;
    #pragma unroll
    for (int q = 0; q < 2; ++q) {
      const int chunk = q * 512 + tid;
      const int row = chunk >> 3, c = chunk & 7;
      const unsigned short* src = code_f16 + (j0 + row) * 768 + k0 + ((c ^ (row & 7)) << 3);
      char* dst = (char*)Alds + (q * 512 + w * 64) * 16;  // wave-uniform base + lane*16
      gload_lds16(src, dst);
    }
  };

  // B' staging for BOTH i: wv/bv loaded once, used for i0 and i1 (amortized).
  auto stageB = [&](int kt) {
    const int k0 = kt << 6;
    const unsigned short* wp = WdT  + (h0 + rg) * 768 + k0 + (c4 << 3);
    const unsigned short* bp = WbcT + (h0 + rg) * 768 + k0 + (c4 << 3);
    const uint4 wv0 = *(const uint4*)wp;
    const uint4 bv0 = *(const uint4*)bp;
    const uint4 wv1 = *(const uint4*)(wp + 64 * 768);
    const uint4 bv1 = *(const uint4*)(bp + 64 * 768);
    const uint4 nv0 = *(const uint4*)(nl_f16 + i0 * 768 + k0 + (c4 << 3));
    const int sw = (c4 ^ (rg & 7)) << 4;   // (rg+64)&7 == rg&7
    {
      uint4 p0, p1;
      asm("v_pk_fma_f16 %0, %1, %2, %3" : "=v"(p0.x) : "v"(nv0.x), "v"(wv0.x), "v"(bv0.x));
      asm("v_pk_fma_f16 %0, %1, %2, %3" : "=v"(p0.y) : "v"(nv0.y), "v"(wv0.y), "v"(bv0.y));
      asm("v_pk_fma_f16 %0, %1, %2, %3" : "=v"(p0.z) : "v"(nv0.z), "v"(wv0.z), "v"(bv0.z));
      asm("v_pk_fma_f16 %0, %1, %2, %3" : "=v"(p0.w) : "v"(nv0.w), "v"(wv0.w), "v"(bv0.w));
      asm("v_pk_fma_f16 %0, %1, %2, %3" : "=v"(p1.x) : "v"(nv0.x), "v"(wv1.x), "v"(bv1.x));
      asm("v_pk_fma_f16 %0, %1, %2, %3" : "=v"(p1.y) : "v"(nv0.y), "v"(wv1.y), "v"(bv1.y));
      asm("v_pk_fma_f16 %0, %1, %2, %3" : "=v"(p1.z) : "v"(nv0.z), "v"(wv1.z), "v"(bv1.z));
      asm("v_pk_fma_f16 %0, %1, %2, %3" : "=v"(p1.w) : "v"(nv0.w), "v"(wv1.w), "v"(bv1.w));
      *(uint4*)((char*)&Blds[0][0] + rg * 128 + sw) = p0;
      *(uint4*)((char*)&Blds[0][0] + (rg + 64) * 128 + sw) = p1;
    }
    const uint4 nv1 = *(const uint4*)(nl_f16 + (i0 + 1) * 768 + k0 + (c4 << 3));
    {
      uint4 p0, p1;
      asm("v_pk_fma_f16 %0, %1, %2, %3" : "=v"(p0.x) : "v"(nv1.x), "v"(wv0.x), "v"(bv0.x));
      asm("v_pk_fma_f16 %0, %1, %2, %3" : "=v"(p0.y) : "v"(nv1.y), "v"(wv0.y), "v"(bv0.y));
      asm("v_pk_fma_f16 %0, %1, %2, %3" : "=v"(p0.z) : "v"(nv1.z), "v"(wv0.z), "v"(bv0.z));
      asm("v_pk_fma_f16 %0, %1, %2, %3" : "=v"(p0.w) : "v"(nv1.w), "v"(wv0.w), "v"(bv0.w));
      asm("v_pk_fma_f16 %0, %1, %2, %3" : "=v"(p1.x) : "v"(nv1.x), "v"(wv1.x), "v"(bv1.x));
      asm("v_pk_fma_f16 %0, %1, %2, %3" : "=v"(p1.y) : "v"(nv1.y), "v"(wv1.y), "v"(bv1.y));
      asm("v_pk_fma_f16 %0, %1, %2, %3" : "=v"(p1.z) : "v"(nv1.z), "v"(wv1.z), "v"(bv1.z));
      asm("v_pk_fma_f16 %0, %1, %2, %3" : "=v"(p1.w) : "v"(nv1.w), "v"(wv1.w), "v"(bv1.w));
      *(uint4*)((char*)&Blds[1][0] + rg * 128 + sw) = p0;
      *(uint4*)((char*)&Blds[1][0] + (rg + 64) * 128 + sw) = p1;
    }
  };

  const unsigned short* Bbase = &Blds[ih][0];

  for (int kt = 0; kt < 12; ++kt) {
    if (kt) __syncthreads();     // all reads of previous tile complete before overwrite
    stage_A(kt);                 // async gload_lds into Alds (in flight during stageB)
    stageB(kt);                  // B' loads -> pk_fma -> ds_write (self-contained)
    __syncthreads();             // staging visible; co-resident block's MFMA covers drain
    #pragma unroll
    for (int ks = 0; ks < 2; ++ks) {
      halfx8 bf[4];
      #pragma unroll
      for (int n = 0; n < 4; ++n) {
        const int row = wc + n * 16 + lr;
        bf[n] = *(const halfx8*)((const char*)Bbase + row * 128 + (((ks * 4 + g) ^ (row & 7)) << 4));
      }
      #pragma unroll
      for (int m = 0; m < 4; ++m) {
        const int row = wr + m * 16 + lr;   // j-local in [0,128)
        halfx8 af = *(const halfx8*)((const char*)Alds + row * 128 + (((ks * 4 + g) ^ (row & 7)) << 4));
        #pragma unroll
        for (int n = 0; n < 4; ++n)
          acc[m][n] = __builtin_amdgcn_mfma_f32_16x16x32_f16(af, bf[n], acc[m][n], 0, 0, 0);
      }
    }
  }

  // ---- epilogue: +lin1+b1 (lin2 folded), tanh, *W2, h-reduce, LDS-combine, atomic ----
  #pragma unroll
  for (int m = 0; m < 4; ++m) {
    #pragma unroll
    for (int reg = 0; reg < 4; ++reg) {
      const int jloc = wr + m * 16 + g * 4 + reg;   // j-local in [0,128)
      float rs = 0.f;
      #pragma unroll
      for (int n = 0; n < 4; ++n) {
        const int cc = wc + n * 16 + lr;
        float x = acc[m][n][reg] + linb[ih][cc];
        x = fminf(fmaxf(x, -15.f), 15.f);
        const float e = __expf(2.f * x);
        rs += __fdividef(e - 1.f, e + 1.f) * w2s[cc];
      }
      rs += __shfl_xor(rs, 1); rs += __shfl_xor(rs, 2);
      rs += __shfl_xor(rs, 4); rs += __shfl_xor(rs, 8);
      if (lr == 0) part[ih][wcIdx][jloc] = rs;
    }
  }
  __syncthreads();
  if (tid < 256) {
    const int ihh = tid >> 7, jj = tid & 127;
    atomicAdd(&s_sum[(i0 + ihh) * 256 + j0 + jj], part[ihh][0][jj] + part[ihh][1][jj]);
  }
}

// ================= fused losses =================
__global__ __launch_bounds__(256) void k_loss(const float* __restrict__ G,
    const float* __restrict__ invc, const float* __restrict__ invn, const float* __restrict__ inva,
    const float* __restrict__ s_sum, const float* __restrict__ b2, float* __restrict__ acc) {
  __shared__ float sred[4];
  __shared__ float dvals[3];
  const int t = threadIdx.x;
  if (blockIdx.x < 256) {
    const int i = blockIdx.x;
    const float* Snc = G;
    const float* Scc = G + 65536;
    const float* Snn = G + 131072;
    const float* Sca = G + 196608;
    const float* Sna = G + 262144;
    const float ici = invc[i], ini = invn[i];
    const float ict = invc[t], intt = invn[t], iat = inva[t];
    const float snc_it = Snc[i * 256 + t];
    const float snc_ti = Snc[t * 256 + i];
    const float e1 = snc_ti * ici * intt * INVT;
    const float e2 = (t == i) ? 0.f : 0.8f * INVT * Scc[i * 256 + t] * ici * ict;
    const float e3 = 0.1f * INVT * Sca[i * 256 + t] * ici * iat;
    const float f1 = snc_it * ini * ict * INVT;
    const float f2 = (t == i) ? 0.f : 0.8f * INVT * Snn[i * 256 + t] * ini * intt;
    const float f3 = 0.1f * INVT * Sna[i * 256 + t] * ini * iat;

    const float Mce = block_max(snc_it, sred);
    const float Mco = block_max(fmaxf(fmaxf(e1, e2), e3), sred);
    const float Mnl = block_max(fmaxf(fmaxf(f1, f2), f3), sred);
    const float Sce = block_sum(expf(snc_it - Mce), sred);
    const float Sco = block_sum(expf(e1 - Mco) + expf(e2 - Mco) + expf(e3 - Mco), sred);
    const float Snl = block_sum(expf(f1 - Mnl) + expf(f2 - Mnl) + expf(f3 - Mnl), sred);
    if (t == i) {
      dvals[0] = snc_it;
      dvals[1] = expf(e1 - Mco) + expf(e3 - Mco);
      dvals[2] = expf(f1 - Mnl) + expf(f3 - Mnl);
    }
    __syncthreads();
    if (t == 0) {
      atomicAdd(&acc[0], Mce + logf(Sce) - dvals[0]);
      atomicAdd(&acc[1], logf(Sco) - logf(dvals[1]));
      atomicAdd(&acc[2], logf(Snl) - logf(dvals[2]));
    }
  } else {
    const int r = (blockIdx.x - 256) * 256 + t;
    const int i = r >> 8, j = r & 255;
    const float s = s_sum[r] + b2[0];
    const float logit = 1.f / (1.f + expf(-s));
    const float pos = (i == j) ? logf(logit + EPSV) : 0.f;
    const float neg = (i == j) ? 0.f : logf(1.f - logit + EPSV);
    const float ps = block_sum(pos, sred);
    const float ns = block_sum(neg, sred);
    if (t == 0) { atomicAdd(&acc[3], ps); atomicAdd(&acc[4], ns); }
  }
}

// ================= final combine =================
__global__ void k_final(const float* __restrict__ acc, float* __restrict__ out) {
  if (threadIdx.x == 0 && blockIdx.x == 0) {
    const float lce = acc[0] * (1.f / 256.f);
    const float lclr = (acc[1] * (1.f / 256.f) + acc[2] * (1.f / 256.f)) * 0.5f;
    const float lcls = -(acc[4] * (1.f / (256.f * 255.f)) + acc[3] * (1.f / 256.f));
    out[0] = lce + 0.1f * lclr + lcls;
  }
}

extern "C" void kernel_launch(void* const* d_in, const int* in_sizes, int n_in,
                              void* d_out, int out_size, void* d_ws, size_t ws_size,
                              hipStream_t stream) {
  const float* code = (const float*)d_in[0];
  const float* nl   = (const float*)d_in[1];
  const float* aug  = (const float*)d_in[2];
  const float* W1   = (const float*)d_in[3];
  const float* b1   = (const float*)d_in[4];
  const float* W2   = (const float*)d_in[5];
  const float* b2   = (const float*)d_in[6];
  float* out = (float*)d_out;
  char* ws = (char*)d_ws;

  unsigned short* WdT      = (unsigned short*)(ws + 0);        // 1,179,648 B
  unsigned short* WbcT     = (unsigned short*)(ws + 1179648);  // 1,179,648 B
  unsigned short* code_f16 = (unsigned short*)(ws + 2359296);  // 393,216 B
  unsigned short* nl_f16   = (unsigned short*)(ws + 2752512);  // 393,216 B
  unsigned short* lin1_f16 = (unsigned short*)(ws + 3145728);  // 393,216 B
  float* G    = (float*)(ws + 3538944);                        // 1,310,720 B
  float* invc = (float*)(ws + 4849664);
  float* invn = (float*)(ws + 4850688);
  float* inva = (float*)(ws + 4851712);
  float* s_sum = (float*)(ws + 4852736);                       // 262,144 B
  float* acc   = (float*)(ws + 5114880);                       // 64 B  (total 5,114,944)

  k_prep<<<2592, 256, 0, stream>>>(code, nl, aug, W1, code_f16, nl_f16, WdT, WbcT,
                                   lin1_f16, invc, invn, inva, G, out, s_sum, acc);
  k_pair<<<1536, 512, 0, stream>>>(code_f16, nl_f16, WdT, WbcT, lin1_f16, b1, W2, s_sum);
  k_loss<<<512, 256, 0, stream>>>(G, invc, invn, inva, s_sum, b2, acc);
  k_final<<<1, 1, 0, stream>>>(acc, out);
}